// Round 5
// baseline (110.841 us; speedup 1.0000x reference)
//
#include <hip/hip_runtime.h>

#define BATCH 8
#define NPTS 4096
#define KSEL 5          // K_NN; self-candidate excluded in-scan
#define ALPHA 1.05f
#define NSEG 16         // candidate-scan split per point (one wave each)
#define SEGLEN (NPTS / NSEG)   // 256
#define TPB (NSEG * 64)        // 1024 threads

// ---------------------------------------------------------------------------
// f32 3-input min/med/max (single VOP3 instr each).
// R4 post-mortem model: VALU instrs cost ~4 cyc issue regardless of class;
// minimize COUNT. The min3/med3/max3 insert network is count-optimal.
// Selection now runs in FLOAT domain (g-scores can be negative, so the
// uint-bit-order trick no longer applies). No NaNs present.
// ---------------------------------------------------------------------------
static __device__ __forceinline__ float min3f(float a, float b, float c) {
  float d;
  asm("v_min3_f32 %0, %1, %2, %3" : "=v"(d) : "v"(a), "v"(b), "v"(c));
  return d;
}
static __device__ __forceinline__ float med3f(float a, float b, float c) {
  float d;
  asm("v_med3_f32 %0, %1, %2, %3" : "=v"(d) : "v"(a), "v"(b), "v"(c));
  return d;
}
static __device__ __forceinline__ float max3f(float a, float b, float c) {
  float d;
  asm("v_max3_f32 %0, %1, %2, %3" : "=v"(d) : "v"(a), "v"(b), "v"(c));
  return d;
}

#define FINF 0x7F800000u   // +inf bit pattern (uint path, fallback kernel)

// uint helpers (fallback LDS kernel only).
static __device__ __forceinline__ unsigned min3u(unsigned a, unsigned b, unsigned c) {
  unsigned d;
  asm("v_min3_u32 %0, %1, %2, %3" : "=v"(d) : "v"(a), "v"(b), "v"(c));
  return d;
}
static __device__ __forceinline__ unsigned med3u(unsigned a, unsigned b, unsigned c) {
  unsigned d;
  asm("v_med3_u32 %0, %1, %2, %3" : "=v"(d) : "v"(a), "v"(b), "v"(c));
  return d;
}
static __device__ __forceinline__ unsigned max3u(unsigned a, unsigned b, unsigned c) {
  unsigned d;
  asm("v_max3_u32 %0, %1, %2, %3" : "=v"(d) : "v"(a), "v"(b), "v"(c));
  return d;
}
static __device__ __forceinline__ unsigned umn(unsigned a, unsigned b) { return a < b ? a : b; }
static __device__ __forceinline__ unsigned umx(unsigned a, unsigned b) { return a > b ? a : b; }

typedef float v2f __attribute__((ext_vector_type(2)));

// Packed dual-FP32 via asm (fallback kernel only; hot path uses compiler IR).
static __device__ __forceinline__ v2f pk_add(v2f a, v2f b) {
  v2f d;
  asm("v_pk_add_f32 %0, %1, %2" : "=v"(d) : "v"(a), "v"(b));
  return d;
}
static __device__ __forceinline__ v2f pk_mul(v2f a, v2f b) {
  v2f d;
  asm("v_pk_mul_f32 %0, %1, %2" : "=v"(d) : "v"(a), "v"(b));
  return d;
}
static __device__ __forceinline__ v2f pk_fma(v2f a, v2f b, v2f c) {
  v2f d;
  asm("v_pk_fma_f32 %0, %1, %2, %3" : "=v"(d) : "v"(a), "v"(b), "v"(c));
  return d;
}

// Fused branchless insert of two candidates into sorted m[0..KSEL-1], float.
static __device__ __forceinline__ void insert2f(float m[KSEL], float tA, float tB) {
#pragma unroll
  for (int k = 0; k < KSEL - 1; ++k) {
    const float mk = m[k];
    m[k] = min3f(mk, tA, tB);
    const float nA = med3f(mk, tA, tB);
    const float nB = max3f(mk, tA, tB);
    tA = nA;
    tB = nB;
  }
  m[KSEL - 1] = min3f(m[KSEL - 1], tA, tB);
}

// uint variant (fallback kernel).
static __device__ __forceinline__ void insert2(unsigned m[KSEL], unsigned tA, unsigned tB) {
#pragma unroll
  for (int k = 0; k < KSEL - 1; ++k) {
    const unsigned mk = m[k];
    m[k] = min3u(mk, tA, tB);
    const unsigned nA = med3u(mk, tA, tB);
    const unsigned nB = max3u(mk, tA, tB);
    tA = nA;
    tB = nB;
  }
  m[KSEL - 1] = min3u(m[KSEL - 1], tA, tB);
}

// ---------------------------------------------------------------------------
// Fast-path scan. R4 keeps: s_load streaming (SGPR pipe), depth-2 rotation
// prefetch (hides ~200cy SMEM latency), schedulable IR (94% VALUBusy).
// New vs R4 (instruction-count cuts, ~4cyc/instr empirically uniform):
//  * expansion-form ranking: g(j) = r_j - 2*dot(p_i,p_j) with r_j
//    precomputed (SGPR stream). d = g + r_i and r_i is per-lane constant, so
//    g-order == d-order; r_i re-added once at the end. 6 -> 4 ops/candidate.
//  * dot-chain written as float2 ext-vector ops (+ __builtin_elementwise_fma)
//    so LLVM can emit v_pk_{mul,fma}_f32 as schedulable IR: 4 -> 2 instrs per
//    candidate-pair in the best case; falls back to R4-equivalent scalar.
// ---------------------------------------------------------------------------
template <bool EXCL>
static __device__ __forceinline__ void scan_seg_pk(const float4* __restrict__ xs4,
                                                   const float4* __restrict__ ys4,
                                                   const float4* __restrict__ zs4,
                                                   const float4* __restrict__ rs4,
                                                   const int j0, const int i,
                                                   const float xi, const float yi, const float zi,
                                                   float m[KSEL]) {
  const int NG = SEGLEN / 4;  // 64 groups of 4 candidates
  const v2f xi2 = {xi, xi};
  const v2f yi2 = {yi, yi};
  const v2f zi2 = {zi, zi};
  const v2f n22 = {-2.0f, -2.0f};

  float4 a0x = xs4[0], a0y = ys4[0], a0z = zs4[0], a0r = rs4[0];
  float4 a1x = xs4[1], a1y = ys4[1], a1z = zs4[1], a1r = rs4[1];
#pragma unroll 4
  for (int q = 0; q < NG; ++q) {
    const float4 cx = a0x, cy = a0y, cz = a0z, cr = a0r;
    a0x = a1x; a0y = a1y; a0z = a1z; a0r = a1r;
    const int qn = (q + 2 < NG) ? (q + 2) : (NG - 1);  // clamped tail
    a1x = xs4[qn]; a1y = ys4[qn]; a1z = zs4[qn]; a1r = rs4[qn];

    const v2f cx01 = {cx.x, cx.y}, cx23 = {cx.z, cx.w};
    const v2f cy01 = {cy.x, cy.y}, cy23 = {cy.z, cy.w};
    const v2f cz01 = {cz.x, cz.y}, cz23 = {cz.z, cz.w};
    const v2f cr01 = {cr.x, cr.y}, cr23 = {cr.z, cr.w};

    v2f t01 = cx01 * xi2;
    v2f t23 = cx23 * xi2;
    t01 = __builtin_elementwise_fma(cy01, yi2, t01);
    t23 = __builtin_elementwise_fma(cy23, yi2, t23);
    t01 = __builtin_elementwise_fma(cz01, zi2, t01);
    t23 = __builtin_elementwise_fma(cz23, zi2, t23);
    const v2f g01 = __builtin_elementwise_fma(t01, n22, cr01);  // r_j - 2*dot
    const v2f g23 = __builtin_elementwise_fma(t23, n22, cr23);

    float gA = g01.x, gB = g01.y, gC = g23.x, gD = g23.y;
    if (EXCL) {
      const int jb = j0 + 4 * q;
      if (jb + 0 == i) gA = __builtin_inff();
      if (jb + 1 == i) gB = __builtin_inff();
      if (jb + 2 == i) gC = __builtin_inff();
      if (jb + 3 == i) gD = __builtin_inff();
    }

    insert2f(m, gA, gB);
    insert2f(m, gC, gD);
  }
}

// ---------------------------------------------------------------------------
// SoA transpose + squared-norm: pc [8][4096][3] -> xs/ys/zs/rs [8*4096].
// Runs once before the knn kernel. Also zeroes out[0].
// ---------------------------------------------------------------------------
__global__ __launch_bounds__(256) void soa_kernel(const float* __restrict__ pc,
                                                  float* __restrict__ xs,
                                                  float* __restrict__ ys,
                                                  float* __restrict__ zs,
                                                  float* __restrict__ rs,
                                                  float* __restrict__ out) {
  const int idx = blockIdx.x * 256 + threadIdx.x;  // 0..32767
  if (idx == 0) out[0] = 0.0f;
  const float x = pc[idx * 3 + 0];
  const float y = pc[idx * 3 + 1];
  const float z = pc[idx * 3 + 2];
  xs[idx] = x;
  ys[idx] = y;
  zs[idx] = z;
  rs[idx] = fmaf(z, z, fmaf(y, y, x * x));
}

// ---------------------------------------------------------------------------
// Kernel 1 (fast path): per-point mean 5-NN squared distance.
// grid = 512 blocks, block = 1024 threads (16 waves). LDS = merge buffer only
// (20 KB, 2 blocks/CU). Candidates streamed via SMEM (see scan_seg_pk).
// ---------------------------------------------------------------------------
__global__ __launch_bounds__(TPB) void knn_value_pk(const float* __restrict__ xs,
                                                    const float* __restrict__ ys,
                                                    const float* __restrict__ zs,
                                                    const float* __restrict__ rs,
                                                    float* __restrict__ value) {
  __shared__ float cand[NSEG][64][KSEL];  // 20 KB

  const int tid = threadIdx.x;
  const int pt  = tid & 63;
  const int seg = __builtin_amdgcn_readfirstlane(tid >> 6);  // wave-uniform
  const int b    = blockIdx.x >> 6;
  const int tile = blockIdx.x & 63;
  const int i    = tile * 64 + pt;

  const float* __restrict__ xb = xs + b * NPTS;
  const float* __restrict__ yb = ys + b * NPTS;
  const float* __restrict__ zb = zs + b * NPTS;
  const float* __restrict__ rb = rs + b * NPTS;

  const float xi = xb[i];
  const float yi = yb[i];
  const float zi = zb[i];

  float m[KSEL];
#pragma unroll
  for (int k = 0; k < KSEL; ++k) m[k] = __builtin_inff();

  const int j0 = seg * SEGLEN;
  const float4* __restrict__ xs4 = (const float4*)(xb + j0);
  const float4* __restrict__ ys4 = (const float4*)(yb + j0);
  const float4* __restrict__ zs4 = (const float4*)(zb + j0);
  const float4* __restrict__ rs4 = (const float4*)(rb + j0);

  // Tile's own 64 indices all fall in segment tile>>2 (SEGLEN=256): only that
  // wave pays the self-exclusion compares.
  if (seg == (tile >> 2)) {
    scan_seg_pk<true>(xs4, ys4, zs4, rs4, j0, i, xi, yi, zi, m);
  } else {
    scan_seg_pk<false>(xs4, ys4, zs4, rs4, j0, i, xi, yi, zi, m);
  }

#pragma unroll
  for (int k = 0; k < KSEL; ++k) cand[seg][pt][k] = m[k];
  __syncthreads();

  // Tree-merge the 16 sorted lists per point: 8,4,2,1 pairwise merges.
  for (int st = 1; st < NSEG; st <<= 1) {
    const int pairs = NSEG / (2 * st);
    if (tid < pairs * 64) {
      const int q = tid >> 6;
      const int p = tid & 63;
      float* A = &cand[2 * st * q][p][0];
      const float* B = &cand[2 * st * q + st][p][0];
      float mm[KSEL];
#pragma unroll
      for (int k = 0; k < KSEL; ++k) mm[k] = A[k];
#pragma unroll
      for (int k = 0; k < KSEL; ++k) {
        float t = B[k];
#pragma unroll
        for (int u = 0; u < KSEL - 1; ++u) {
          const float lo = fminf(mm[u], t);
          t = fmaxf(mm[u], t);
          mm[u] = lo;
        }
        mm[KSEL - 1] = fminf(mm[KSEL - 1], t);
      }
#pragma unroll
      for (int k = 0; k < KSEL; ++k) A[k] = mm[k];
    }
    __syncthreads();
  }

  // mean(d) = mean(g) + r_i (g-order == d-order; r_i constant per point).
  if (tid < 64) {
    const int ii = tile * 64 + tid;
    float s5 = 0.f;
#pragma unroll
    for (int k = 0; k < KSEL; ++k) s5 += cand[0][tid][k];
    value[b * NPTS + ii] = s5 * 0.2f + rb[ii];
  }
}

// ---------------------------------------------------------------------------
// Fallback (ws too small for SoA): R1-style kernel, LDS-staged candidates,
// (a-b)^2 distances ranked via the uint-order trick. Unchanged.
// ---------------------------------------------------------------------------
template <bool EXCL>
static __device__ __forceinline__ void scan_seg_l(const float* __restrict__ xs,
                                                  const float* __restrict__ ys,
                                                  const float* __restrict__ zs,
                                                  const int j0, const int i,
                                                  const v2f nx2, const v2f ny2, const v2f nz2,
                                                  unsigned m[KSEL]) {
#pragma unroll 4
  for (int jj = 0; jj < SEGLEN; jj += 4) {
    const float4 cx = *(const float4*)&xs[j0 + jj];
    const float4 cy = *(const float4*)&ys[j0 + jj];
    const float4 cz = *(const float4*)&zs[j0 + jj];

    const v2f cxAB = {cx.x, cx.y}, cxCD = {cx.z, cx.w};
    const v2f cyAB = {cy.x, cy.y}, cyCD = {cy.z, cy.w};
    const v2f czAB = {cz.x, cz.y}, czCD = {cz.z, cz.w};

    const v2f dx0 = pk_add(cxAB, nx2);
    const v2f dx1 = pk_add(cxCD, nx2);
    const v2f dy0 = pk_add(cyAB, ny2);
    const v2f dy1 = pk_add(cyCD, ny2);
    const v2f dz0 = pk_add(czAB, nz2);
    const v2f dz1 = pk_add(czCD, nz2);

    v2f d0 = pk_mul(dx0, dx0);
    v2f d1 = pk_mul(dx1, dx1);
    d0 = pk_fma(dy0, dy0, d0);
    d1 = pk_fma(dy1, dy1, d1);
    d0 = pk_fma(dz0, dz0, d0);
    d1 = pk_fma(dz1, dz1, d1);

    unsigned uA = __float_as_uint(d0.x);
    unsigned uB = __float_as_uint(d0.y);
    unsigned uC = __float_as_uint(d1.x);
    unsigned uD = __float_as_uint(d1.y);
    if (EXCL) {
      const int jb = j0 + jj;
      if (jb + 0 == i) uA = FINF;
      if (jb + 1 == i) uB = FINF;
      if (jb + 2 == i) uC = FINF;
      if (jb + 3 == i) uD = FINF;
    }

    insert2(m, uA, uB);
    insert2(m, uC, uD);
  }
}

__global__ __launch_bounds__(TPB) void knn_value_lds(const float* __restrict__ pc,
                                                     float* __restrict__ value,
                                                     float* __restrict__ out) {
  __shared__ union __align__(16) {
    struct { float xs[NPTS]; float ys[NPTS]; float zs[NPTS]; } s;  // 48 KB
    unsigned cand[NSEG][64][KSEL];                                 // 20 KB
  } sh;

  const int tid = threadIdx.x;
  const int pt  = tid & 63;
  const int seg = __builtin_amdgcn_readfirstlane(tid >> 6);
  const int b    = blockIdx.x >> 6;
  const int tile = blockIdx.x & 63;
  const int i    = tile * 64 + pt;

  if (blockIdx.x == 0 && tid == 0) out[0] = 0.0f;

  const float* __restrict__ base = pc + (size_t)b * (NPTS * 3);

#pragma unroll
  for (int p = 0; p < NPTS / TPB; ++p) {
    const int idx = tid + p * TPB;
    sh.s.xs[idx] = base[idx * 3 + 0];
    sh.s.ys[idx] = base[idx * 3 + 1];
    sh.s.zs[idx] = base[idx * 3 + 2];
  }
  __syncthreads();

  const float xi = sh.s.xs[i];
  const float yi = sh.s.ys[i];
  const float zi = sh.s.zs[i];
  const v2f nx2 = {-xi, -xi};
  const v2f ny2 = {-yi, -yi};
  const v2f nz2 = {-zi, -zi};

  unsigned m[KSEL];
#pragma unroll
  for (int k = 0; k < KSEL; ++k) m[k] = FINF;

  const int j0 = seg * SEGLEN;
  if (seg == (tile >> 2)) {
    scan_seg_l<true>(sh.s.xs, sh.s.ys, sh.s.zs, j0, i, nx2, ny2, nz2, m);
  } else {
    scan_seg_l<false>(sh.s.xs, sh.s.ys, sh.s.zs, j0, i, nx2, ny2, nz2, m);
  }
  __syncthreads();

#pragma unroll
  for (int k = 0; k < KSEL; ++k) sh.cand[seg][pt][k] = m[k];
  __syncthreads();

  for (int st = 1; st < NSEG; st <<= 1) {
    const int pairs = NSEG / (2 * st);
    if (tid < pairs * 64) {
      const int q = tid >> 6;
      const int p = tid & 63;
      unsigned* A = &sh.cand[2 * st * q][p][0];
      const unsigned* B = &sh.cand[2 * st * q + st][p][0];
      unsigned mm[KSEL];
#pragma unroll
      for (int k = 0; k < KSEL; ++k) mm[k] = A[k];
#pragma unroll
      for (int k = 0; k < KSEL; ++k) {
        unsigned t = B[k];
#pragma unroll
        for (int u = 0; u < KSEL - 1; ++u) {
          const unsigned lo = umn(mm[u], t);
          t = umx(mm[u], t);
          mm[u] = lo;
        }
        mm[KSEL - 1] = umn(mm[KSEL - 1], t);
      }
#pragma unroll
      for (int k = 0; k < KSEL; ++k) A[k] = mm[k];
    }
    __syncthreads();
  }

  if (tid < 64) {
    float s5 = 0.f;
#pragma unroll
    for (int k = 0; k < KSEL; ++k) s5 += __uint_as_float(sh.cand[0][tid][k]);
    value[b * NPTS + tile * 64 + tid] = s5 * 0.2f;
  }
}

// ---------------------------------------------------------------------------
// Kernel 2: per-batch stats + masked mean * weight -> atomicAdd into out.
// UNCHANGED.
// ---------------------------------------------------------------------------
__global__ __launch_bounds__(256) void stats_kernel(const float* __restrict__ value,
                                                    const float* __restrict__ weights,
                                                    float* __restrict__ out) {
  __shared__ float red[256];
  const int b   = blockIdx.x;
  const int tid = threadIdx.x;
  const float* __restrict__ v = value + b * NPTS;

  float s = 0.f;
  for (int j = tid; j < NPTS; j += 256) s += v[j];
  red[tid] = s;
  __syncthreads();
  for (int off = 128; off > 0; off >>= 1) {
    if (tid < off) red[tid] += red[tid + off];
    __syncthreads();
  }
  const float mean = red[0] * (1.0f / NPTS);
  __syncthreads();

  float s2 = 0.f;
  for (int j = tid; j < NPTS; j += 256) {
    const float d = v[j] - mean;
    s2 += d * d;
  }
  red[tid] = s2;
  __syncthreads();
  for (int off = 128; off > 0; off >>= 1) {
    if (tid < off) red[tid] += red[tid + off];
    __syncthreads();
  }
  const float thr = mean + ALPHA * sqrtf(red[0] * (1.0f / (NPTS - 1)));
  __syncthreads();

  float s3 = 0.f;
  for (int j = tid; j < NPTS; j += 256) {
    const float vv = v[j];
    if (vv > thr) s3 += vv;
  }
  red[tid] = s3;
  __syncthreads();
  for (int off = 128; off > 0; off >>= 1) {
    if (tid < off) red[tid] += red[tid + off];
    __syncthreads();
  }
  if (tid == 0) {
    atomicAdd(out, red[0] * (1.0f / NPTS) * weights[b] * (1.0f / BATCH));
  }
}

extern "C" void kernel_launch(void* const* d_in, const int* in_sizes, int n_in,
                              void* d_out, int out_size, void* d_ws, size_t ws_size,
                              hipStream_t stream) {
  const float* pc      = (const float*)d_in[0];   // [8,4096,3] f32
  const float* weights = (const float*)d_in[1];   // [8] f32
  float* out   = (float*)d_out;                   // scalar f32
  float* wsf   = (float*)d_ws;

  const size_t NB = (size_t)BATCH * NPTS;         // 32768
  const size_t need = NB * 5 * sizeof(float);     // value + xs + ys + zs + rs = 640 KB

  if (ws_size >= need) {
    float* value = wsf;
    float* xs = wsf + NB;
    float* ys = wsf + 2 * NB;
    float* zs = wsf + 3 * NB;
    float* rs = wsf + 4 * NB;
    soa_kernel<<<dim3(BATCH * NPTS / 256), dim3(256), 0, stream>>>(pc, xs, ys, zs, rs, out);
    knn_value_pk<<<dim3(BATCH * (NPTS / 64)), dim3(TPB), 0, stream>>>(xs, ys, zs, rs, value);
    stats_kernel<<<dim3(BATCH), dim3(256), 0, stream>>>(value, weights, out);
  } else {
    float* value = wsf;                           // 128 KB (R1 layout)
    knn_value_lds<<<dim3(BATCH * (NPTS / 64)), dim3(TPB), 0, stream>>>(pc, value, out);
    stats_kernel<<<dim3(BATCH), dim3(256), 0, stream>>>(value, weights, out);
  }
}

// Round 6
// 106.951 us; speedup vs baseline: 1.0364x; 1.0364x over previous
//
#include <hip/hip_runtime.h>

#define BATCH 8
#define NPTS 4096
#define KSEL 5          // K_NN; self-candidate excluded in-scan
#define ALPHA 1.05f
#define NSEG 16         // candidate-scan split per point (one wave each)
#define SEGLEN (NPTS / NSEG)   // 256
#define TPB (NSEG * 64)        // 1024 threads

// ---------------------------------------------------------------------------
// f32 3-input min/med/max (single VOP3 instr each). Selection runs in FLOAT
// domain (g-scores can be negative). No NaNs present.
// ---------------------------------------------------------------------------
static __device__ __forceinline__ float min3f(float a, float b, float c) {
  float d;
  asm("v_min3_f32 %0, %1, %2, %3" : "=v"(d) : "v"(a), "v"(b), "v"(c));
  return d;
}
static __device__ __forceinline__ float med3f(float a, float b, float c) {
  float d;
  asm("v_med3_f32 %0, %1, %2, %3" : "=v"(d) : "v"(a), "v"(b), "v"(c));
  return d;
}
static __device__ __forceinline__ float max3f(float a, float b, float c) {
  float d;
  asm("v_max3_f32 %0, %1, %2, %3" : "=v"(d) : "v"(a), "v"(b), "v"(c));
  return d;
}

#define FINF 0x7F800000u   // +inf bit pattern (uint path, fallback kernel)

// uint helpers (fallback LDS kernel only).
static __device__ __forceinline__ unsigned min3u(unsigned a, unsigned b, unsigned c) {
  unsigned d;
  asm("v_min3_u32 %0, %1, %2, %3" : "=v"(d) : "v"(a), "v"(b), "v"(c));
  return d;
}
static __device__ __forceinline__ unsigned med3u(unsigned a, unsigned b, unsigned c) {
  unsigned d;
  asm("v_med3_u32 %0, %1, %2, %3" : "=v"(d) : "v"(a), "v"(b), "v"(c));
  return d;
}
static __device__ __forceinline__ unsigned max3u(unsigned a, unsigned b, unsigned c) {
  unsigned d;
  asm("v_max3_u32 %0, %1, %2, %3" : "=v"(d) : "v"(a), "v"(b), "v"(c));
  return d;
}
static __device__ __forceinline__ unsigned umn(unsigned a, unsigned b) { return a < b ? a : b; }
static __device__ __forceinline__ unsigned umx(unsigned a, unsigned b) { return a > b ? a : b; }

typedef float v2f  __attribute__((ext_vector_type(2)));
typedef float f16v __attribute__((ext_vector_type(16)));  // 64 B, one s_load_dwordx16

// Packed dual-FP32 via asm (fallback kernel only; hot path uses compiler IR).
static __device__ __forceinline__ v2f pk_add(v2f a, v2f b) {
  v2f d;
  asm("v_pk_add_f32 %0, %1, %2" : "=v"(d) : "v"(a), "v"(b));
  return d;
}
static __device__ __forceinline__ v2f pk_mul(v2f a, v2f b) {
  v2f d;
  asm("v_pk_mul_f32 %0, %1, %2" : "=v"(d) : "v"(a), "v"(b));
  return d;
}
static __device__ __forceinline__ v2f pk_fma(v2f a, v2f b, v2f c) {
  v2f d;
  asm("v_pk_fma_f32 %0, %1, %2, %3" : "=v"(d) : "v"(a), "v"(b), "v"(c));
  return d;
}

// Fused branchless insert of two candidates into sorted m[0..KSEL-1], float.
static __device__ __forceinline__ void insert2f(float m[KSEL], float tA, float tB) {
#pragma unroll
  for (int k = 0; k < KSEL - 1; ++k) {
    const float mk = m[k];
    m[k] = min3f(mk, tA, tB);
    const float nA = med3f(mk, tA, tB);
    const float nB = max3f(mk, tA, tB);
    tA = nA;
    tB = nB;
  }
  m[KSEL - 1] = min3f(m[KSEL - 1], tA, tB);
}

// uint variant (fallback kernel).
static __device__ __forceinline__ void insert2(unsigned m[KSEL], unsigned tA, unsigned tB) {
#pragma unroll
  for (int k = 0; k < KSEL - 1; ++k) {
    const unsigned mk = m[k];
    m[k] = min3u(mk, tA, tB);
    const unsigned nA = med3u(mk, tA, tB);
    const unsigned nB = max3u(mk, tA, tB);
    tA = nA;
    tB = nB;
  }
  m[KSEL - 1] = min3u(m[KSEL - 1], tA, tB);
}

// ---------------------------------------------------------------------------
// Fast-path scan. R5 post-mortem: VALU floor (~29us busy) was reached but the
// SCALAR pipe saturated — 4 s_load_dwordx4 + ~4 SALU per group from 32
// waves/CU demanded ~1.3 scalar-issue/cyc vs ~1.0 capacity. Fix: ONE
// interleaved 64B group {x[4],y[4],z[4],r[4]} -> one s_load_dwordx16 + one
// address stream per group (~0.45/cyc demand). VALU unchanged: 8 pk ops for
// g(j) = r_j - 2*dot(p_i,p_j) (each VOP3P reads <=1 SGPR-pair operand), plus
// the 26-op selection network. Depth-2 rotation prefetch retained.
// ---------------------------------------------------------------------------
template <bool EXCL>
static __device__ __forceinline__ void scan_seg_p16(const f16v* __restrict__ pk16,
                                                    const int j0, const int i,
                                                    const v2f x2, const v2f y2, const v2f z2,
                                                    float m[KSEL]) {
  const int NG = SEGLEN / 4;  // 64 groups of 4 candidates
  f16v a0 = pk16[0];
  f16v a1 = pk16[1];
#pragma unroll 4
  for (int q = 0; q < NG; ++q) {
    const f16v c = a0;
    a0 = a1;
    const int qn = (q + 2 < NG) ? (q + 2) : (NG - 1);  // clamped tail
    a1 = pk16[qn];

    // layout: c[0..3]=x, c[4..7]=y, c[8..11]=z, c[12..15]=r
    v2f t01 = (v2f){c[0], c[1]} * x2;                         // x_j * (-2 x_i)
    v2f t23 = (v2f){c[2], c[3]} * x2;
    t01 = __builtin_elementwise_fma((v2f){c[4], c[5]}, y2, t01);
    t23 = __builtin_elementwise_fma((v2f){c[6], c[7]}, y2, t23);
    t01 = __builtin_elementwise_fma((v2f){c[8], c[9]}, z2, t01);
    t23 = __builtin_elementwise_fma((v2f){c[10], c[11]}, z2, t23);
    const v2f g01 = t01 + (v2f){c[12], c[13]};                // + r_j
    const v2f g23 = t23 + (v2f){c[14], c[15]};

    float gA = g01.x, gB = g01.y, gC = g23.x, gD = g23.y;
    if (EXCL) {
      const int jb = j0 + 4 * q;
      if (jb + 0 == i) gA = __builtin_inff();
      if (jb + 1 == i) gB = __builtin_inff();
      if (jb + 2 == i) gC = __builtin_inff();
      if (jb + 3 == i) gD = __builtin_inff();
    }

    insert2f(m, gA, gB);
    insert2f(m, gC, gD);
  }
}

// ---------------------------------------------------------------------------
// Pack: pc [8][4096][3] -> pack[8][1024] of 64B groups {x[4],y[4],z[4],r[4]}.
// One thread per group; runs once before the knn kernel. Also zeroes out[0].
// ---------------------------------------------------------------------------
__global__ __launch_bounds__(256) void pack_kernel(const float* __restrict__ pc,
                                                   float* __restrict__ pack,
                                                   float* __restrict__ out) {
  const int g = blockIdx.x * 256 + threadIdx.x;  // 0..8191 (no group crosses a batch)
  if (g == 0) out[0] = 0.0f;
  const float4 p0 = *(const float4*)(pc + g * 12 + 0);  // x0 y0 z0 x1
  const float4 p1 = *(const float4*)(pc + g * 12 + 4);  // y1 z1 x2 y2
  const float4 p2 = *(const float4*)(pc + g * 12 + 8);  // z2 x3 y3 z3
  const float x0 = p0.x, y0 = p0.y, z0 = p0.z;
  const float x1 = p0.w, y1 = p1.x, z1 = p1.y;
  const float x2 = p1.z, y2 = p1.w, z2 = p2.x;
  const float x3 = p2.y, y3 = p2.z, z3 = p2.w;
  float4* dst = (float4*)(pack + (size_t)g * 16);
  dst[0] = (float4){x0, x1, x2, x3};
  dst[1] = (float4){y0, y1, y2, y3};
  dst[2] = (float4){z0, z1, z2, z3};
  dst[3] = (float4){fmaf(z0, z0, fmaf(y0, y0, x0 * x0)),
                    fmaf(z1, z1, fmaf(y1, y1, x1 * x1)),
                    fmaf(z2, z2, fmaf(y2, y2, x2 * x2)),
                    fmaf(z3, z3, fmaf(y3, y3, x3 * x3))};
}

// ---------------------------------------------------------------------------
// Kernel 1 (fast path): per-point mean 5-NN squared distance.
// grid = 512 blocks, block = 1024 threads (16 waves). LDS = merge buffer only
// (20 KB, 2 blocks/CU). Candidates streamed via s_load_dwordx16.
// ---------------------------------------------------------------------------
__global__ __launch_bounds__(TPB) void knn_value_p16(const float* __restrict__ pack,
                                                     float* __restrict__ value) {
  __shared__ float cand[NSEG][64][KSEL];  // 20 KB

  const int tid = threadIdx.x;
  const int pt  = tid & 63;
  const int seg = __builtin_amdgcn_readfirstlane(tid >> 6);  // wave-uniform
  const int b    = blockIdx.x >> 6;
  const int tile = blockIdx.x & 63;
  const int i    = tile * 64 + pt;

  const float* __restrict__ pb = pack + (size_t)b * (NPTS * 4);  // 1024 groups x 16

  // Per-lane gather of point-i coords from the packed layout (once).
  const int gi = (i >> 2) * 16 + (i & 3);
  const float xi = pb[gi + 0];
  const float yi = pb[gi + 4];
  const float zi = pb[gi + 8];
  // -2*x_i is EXACT (exponent bump + sign), so g = fma(x_j, -2x_i, ...) + r_j.
  const v2f x2 = {-2.0f * xi, -2.0f * xi};
  const v2f y2 = {-2.0f * yi, -2.0f * yi};
  const v2f z2 = {-2.0f * zi, -2.0f * zi};

  float m[KSEL];
#pragma unroll
  for (int k = 0; k < KSEL; ++k) m[k] = __builtin_inff();

  const int j0 = seg * SEGLEN;
  const f16v* __restrict__ pk16 = (const f16v*)(pb) + seg * (SEGLEN / 4);

  // Tile's own 64 indices all fall in segment tile>>2 (SEGLEN=256): only that
  // wave pays the self-exclusion compares.
  if (seg == (tile >> 2)) {
    scan_seg_p16<true>(pk16, j0, i, x2, y2, z2, m);
  } else {
    scan_seg_p16<false>(pk16, j0, i, x2, y2, z2, m);
  }

#pragma unroll
  for (int k = 0; k < KSEL; ++k) cand[seg][pt][k] = m[k];
  __syncthreads();

  // Tree-merge the 16 sorted lists per point: 8,4,2,1 pairwise merges.
  for (int st = 1; st < NSEG; st <<= 1) {
    const int pairs = NSEG / (2 * st);
    if (tid < pairs * 64) {
      const int q = tid >> 6;
      const int p = tid & 63;
      float* A = &cand[2 * st * q][p][0];
      const float* B = &cand[2 * st * q + st][p][0];
      float mm[KSEL];
#pragma unroll
      for (int k = 0; k < KSEL; ++k) mm[k] = A[k];
#pragma unroll
      for (int k = 0; k < KSEL; ++k) {
        float t = B[k];
#pragma unroll
        for (int u = 0; u < KSEL - 1; ++u) {
          const float lo = fminf(mm[u], t);
          t = fmaxf(mm[u], t);
          mm[u] = lo;
        }
        mm[KSEL - 1] = fminf(mm[KSEL - 1], t);
      }
#pragma unroll
      for (int k = 0; k < KSEL; ++k) A[k] = mm[k];
    }
    __syncthreads();
  }

  // mean(d) = mean(g) + r_i. Thread tid (<64) is seg 0, pt = tid: it already
  // holds x/y/z of point i = tile*64+tid; recompute r_i with the SAME fmaf
  // form as pack_kernel (identical bits).
  if (tid < 64) {
    float s5 = 0.f;
#pragma unroll
    for (int k = 0; k < KSEL; ++k) s5 += cand[0][tid][k];
    const float ri = fmaf(zi, zi, fmaf(yi, yi, xi * xi));
    value[b * NPTS + tile * 64 + tid] = s5 * 0.2f + ri;
  }
}

// ---------------------------------------------------------------------------
// Fallback (ws too small): R1-style kernel, LDS-staged candidates,
// (a-b)^2 distances ranked via the uint-order trick. Unchanged.
// ---------------------------------------------------------------------------
template <bool EXCL>
static __device__ __forceinline__ void scan_seg_l(const float* __restrict__ xs,
                                                  const float* __restrict__ ys,
                                                  const float* __restrict__ zs,
                                                  const int j0, const int i,
                                                  const v2f nx2, const v2f ny2, const v2f nz2,
                                                  unsigned m[KSEL]) {
#pragma unroll 4
  for (int jj = 0; jj < SEGLEN; jj += 4) {
    const float4 cx = *(const float4*)&xs[j0 + jj];
    const float4 cy = *(const float4*)&ys[j0 + jj];
    const float4 cz = *(const float4*)&zs[j0 + jj];

    const v2f cxAB = {cx.x, cx.y}, cxCD = {cx.z, cx.w};
    const v2f cyAB = {cy.x, cy.y}, cyCD = {cy.z, cy.w};
    const v2f czAB = {cz.x, cz.y}, czCD = {cz.z, cz.w};

    const v2f dx0 = pk_add(cxAB, nx2);
    const v2f dx1 = pk_add(cxCD, nx2);
    const v2f dy0 = pk_add(cyAB, ny2);
    const v2f dy1 = pk_add(cyCD, ny2);
    const v2f dz0 = pk_add(czAB, nz2);
    const v2f dz1 = pk_add(czCD, nz2);

    v2f d0 = pk_mul(dx0, dx0);
    v2f d1 = pk_mul(dx1, dx1);
    d0 = pk_fma(dy0, dy0, d0);
    d1 = pk_fma(dy1, dy1, d1);
    d0 = pk_fma(dz0, dz0, d0);
    d1 = pk_fma(dz1, dz1, d1);

    unsigned uA = __float_as_uint(d0.x);
    unsigned uB = __float_as_uint(d0.y);
    unsigned uC = __float_as_uint(d1.x);
    unsigned uD = __float_as_uint(d1.y);
    if (EXCL) {
      const int jb = j0 + jj;
      if (jb + 0 == i) uA = FINF;
      if (jb + 1 == i) uB = FINF;
      if (jb + 2 == i) uC = FINF;
      if (jb + 3 == i) uD = FINF;
    }

    insert2(m, uA, uB);
    insert2(m, uC, uD);
  }
}

__global__ __launch_bounds__(TPB) void knn_value_lds(const float* __restrict__ pc,
                                                     float* __restrict__ value,
                                                     float* __restrict__ out) {
  __shared__ union __align__(16) {
    struct { float xs[NPTS]; float ys[NPTS]; float zs[NPTS]; } s;  // 48 KB
    unsigned cand[NSEG][64][KSEL];                                 // 20 KB
  } sh;

  const int tid = threadIdx.x;
  const int pt  = tid & 63;
  const int seg = __builtin_amdgcn_readfirstlane(tid >> 6);
  const int b    = blockIdx.x >> 6;
  const int tile = blockIdx.x & 63;
  const int i    = tile * 64 + pt;

  if (blockIdx.x == 0 && tid == 0) out[0] = 0.0f;

  const float* __restrict__ base = pc + (size_t)b * (NPTS * 3);

#pragma unroll
  for (int p = 0; p < NPTS / TPB; ++p) {
    const int idx = tid + p * TPB;
    sh.s.xs[idx] = base[idx * 3 + 0];
    sh.s.ys[idx] = base[idx * 3 + 1];
    sh.s.zs[idx] = base[idx * 3 + 2];
  }
  __syncthreads();

  const float xi = sh.s.xs[i];
  const float yi = sh.s.ys[i];
  const float zi = sh.s.zs[i];
  const v2f nx2 = {-xi, -xi};
  const v2f ny2 = {-yi, -yi};
  const v2f nz2 = {-zi, -zi};

  unsigned m[KSEL];
#pragma unroll
  for (int k = 0; k < KSEL; ++k) m[k] = FINF;

  const int j0 = seg * SEGLEN;
  if (seg == (tile >> 2)) {
    scan_seg_l<true>(sh.s.xs, sh.s.ys, sh.s.zs, j0, i, nx2, ny2, nz2, m);
  } else {
    scan_seg_l<false>(sh.s.xs, sh.s.ys, sh.s.zs, j0, i, nx2, ny2, nz2, m);
  }
  __syncthreads();

#pragma unroll
  for (int k = 0; k < KSEL; ++k) sh.cand[seg][pt][k] = m[k];
  __syncthreads();

  for (int st = 1; st < NSEG; st <<= 1) {
    const int pairs = NSEG / (2 * st);
    if (tid < pairs * 64) {
      const int q = tid >> 6;
      const int p = tid & 63;
      unsigned* A = &sh.cand[2 * st * q][p][0];
      const unsigned* B = &sh.cand[2 * st * q + st][p][0];
      unsigned mm[KSEL];
#pragma unroll
      for (int k = 0; k < KSEL; ++k) mm[k] = A[k];
#pragma unroll
      for (int k = 0; k < KSEL; ++k) {
        unsigned t = B[k];
#pragma unroll
        for (int u = 0; u < KSEL - 1; ++u) {
          const unsigned lo = umn(mm[u], t);
          t = umx(mm[u], t);
          mm[u] = lo;
        }
        mm[KSEL - 1] = umn(mm[KSEL - 1], t);
      }
#pragma unroll
      for (int k = 0; k < KSEL; ++k) A[k] = mm[k];
    }
    __syncthreads();
  }

  if (tid < 64) {
    float s5 = 0.f;
#pragma unroll
    for (int k = 0; k < KSEL; ++k) s5 += __uint_as_float(sh.cand[0][tid][k]);
    value[b * NPTS + tile * 64 + tid] = s5 * 0.2f;
  }
}

// ---------------------------------------------------------------------------
// Kernel 2: per-batch stats + masked mean * weight -> atomicAdd into out.
// UNCHANGED.
// ---------------------------------------------------------------------------
__global__ __launch_bounds__(256) void stats_kernel(const float* __restrict__ value,
                                                    const float* __restrict__ weights,
                                                    float* __restrict__ out) {
  __shared__ float red[256];
  const int b   = blockIdx.x;
  const int tid = threadIdx.x;
  const float* __restrict__ v = value + b * NPTS;

  float s = 0.f;
  for (int j = tid; j < NPTS; j += 256) s += v[j];
  red[tid] = s;
  __syncthreads();
  for (int off = 128; off > 0; off >>= 1) {
    if (tid < off) red[tid] += red[tid + off];
    __syncthreads();
  }
  const float mean = red[0] * (1.0f / NPTS);
  __syncthreads();

  float s2 = 0.f;
  for (int j = tid; j < NPTS; j += 256) {
    const float d = v[j] - mean;
    s2 += d * d;
  }
  red[tid] = s2;
  __syncthreads();
  for (int off = 128; off > 0; off >>= 1) {
    if (tid < off) red[tid] += red[tid + off];
    __syncthreads();
  }
  const float thr = mean + ALPHA * sqrtf(red[0] * (1.0f / (NPTS - 1)));
  __syncthreads();

  float s3 = 0.f;
  for (int j = tid; j < NPTS; j += 256) {
    const float vv = v[j];
    if (vv > thr) s3 += vv;
  }
  red[tid] = s3;
  __syncthreads();
  for (int off = 128; off > 0; off >>= 1) {
    if (tid < off) red[tid] += red[tid + off];
    __syncthreads();
  }
  if (tid == 0) {
    atomicAdd(out, red[0] * (1.0f / NPTS) * weights[b] * (1.0f / BATCH));
  }
}

extern "C" void kernel_launch(void* const* d_in, const int* in_sizes, int n_in,
                              void* d_out, int out_size, void* d_ws, size_t ws_size,
                              hipStream_t stream) {
  const float* pc      = (const float*)d_in[0];   // [8,4096,3] f32
  const float* weights = (const float*)d_in[1];   // [8] f32
  float* out   = (float*)d_out;                   // scalar f32
  float* wsf   = (float*)d_ws;

  const size_t NB = (size_t)BATCH * NPTS;         // 32768
  const size_t need = NB * 4 + NB * 4 * 4;        // value (128KB) + pack (512KB)

  if (ws_size >= need) {
    float* value = wsf;                           // 32768 floats
    float* pack  = wsf + NB;                      // 131072 floats, 64B aligned
    pack_kernel<<<dim3(BATCH * NPTS / 4 / 256), dim3(256), 0, stream>>>(pc, pack, out);
    knn_value_p16<<<dim3(BATCH * (NPTS / 64)), dim3(TPB), 0, stream>>>(pack, value);
    stats_kernel<<<dim3(BATCH), dim3(256), 0, stream>>>(value, weights, out);
  } else {
    float* value = wsf;                           // 128 KB (R1 layout)
    knn_value_lds<<<dim3(BATCH * (NPTS / 64)), dim3(TPB), 0, stream>>>(pc, value, out);
    stats_kernel<<<dim3(BATCH), dim3(256), 0, stream>>>(value, weights, out);
  }
}

// Round 7
// 106.667 us; speedup vs baseline: 1.0391x; 1.0027x over previous
//
#include <hip/hip_runtime.h>

#define BATCH 8
#define NPTS 4096
#define KSEL 5          // K_NN; self-candidate excluded in-scan
#define ALPHA 1.05f
#define NSEG 16         // candidate-scan split per point (one wave each)
#define SEGLEN (NPTS / NSEG)   // 256
#define TPB (NSEG * 64)        // 1024 threads

// ---------------------------------------------------------------------------
// f32 3-input min/med/max (single VOP3 instr each). Selection runs in FLOAT
// domain (g-scores can be negative). No NaNs present.
// ---------------------------------------------------------------------------
static __device__ __forceinline__ float min3f(float a, float b, float c) {
  float d;
  asm("v_min3_f32 %0, %1, %2, %3" : "=v"(d) : "v"(a), "v"(b), "v"(c));
  return d;
}
static __device__ __forceinline__ float med3f(float a, float b, float c) {
  float d;
  asm("v_med3_f32 %0, %1, %2, %3" : "=v"(d) : "v"(a), "v"(b), "v"(c));
  return d;
}
static __device__ __forceinline__ float max3f(float a, float b, float c) {
  float d;
  asm("v_max3_f32 %0, %1, %2, %3" : "=v"(d) : "v"(a), "v"(b), "v"(c));
  return d;
}

#define FINF 0x7F800000u   // +inf bit pattern (uint path, fallback kernel)

// uint helpers (fallback LDS kernel only).
static __device__ __forceinline__ unsigned min3u(unsigned a, unsigned b, unsigned c) {
  unsigned d;
  asm("v_min3_u32 %0, %1, %2, %3" : "=v"(d) : "v"(a), "v"(b), "v"(c));
  return d;
}
static __device__ __forceinline__ unsigned med3u(unsigned a, unsigned b, unsigned c) {
  unsigned d;
  asm("v_med3_u32 %0, %1, %2, %3" : "=v"(d) : "v"(a), "v"(b), "v"(c));
  return d;
}
static __device__ __forceinline__ unsigned max3u(unsigned a, unsigned b, unsigned c) {
  unsigned d;
  asm("v_max3_u32 %0, %1, %2, %3" : "=v"(d) : "v"(a), "v"(b), "v"(c));
  return d;
}
static __device__ __forceinline__ unsigned umn(unsigned a, unsigned b) { return a < b ? a : b; }
static __device__ __forceinline__ unsigned umx(unsigned a, unsigned b) { return a > b ? a : b; }

typedef float v2f  __attribute__((ext_vector_type(2)));
typedef float f16v __attribute__((ext_vector_type(16)));  // 64 B, one s_load_dwordx16

// Packed dual-FP32 via asm (fallback kernel only; hot path uses compiler IR).
static __device__ __forceinline__ v2f pk_add(v2f a, v2f b) {
  v2f d;
  asm("v_pk_add_f32 %0, %1, %2" : "=v"(d) : "v"(a), "v"(b));
  return d;
}
static __device__ __forceinline__ v2f pk_mul(v2f a, v2f b) {
  v2f d;
  asm("v_pk_mul_f32 %0, %1, %2" : "=v"(d) : "v"(a), "v"(b));
  return d;
}
static __device__ __forceinline__ v2f pk_fma(v2f a, v2f b, v2f c) {
  v2f d;
  asm("v_pk_fma_f32 %0, %1, %2, %3" : "=v"(d) : "v"(a), "v"(b), "v"(c));
  return d;
}

// Fused branchless insert of two candidates into sorted m[0..KSEL-1], float.
static __device__ __forceinline__ void insert2f(float m[KSEL], float tA, float tB) {
#pragma unroll
  for (int k = 0; k < KSEL - 1; ++k) {
    const float mk = m[k];
    m[k] = min3f(mk, tA, tB);
    const float nA = med3f(mk, tA, tB);
    const float nB = max3f(mk, tA, tB);
    tA = nA;
    tB = nB;
  }
  m[KSEL - 1] = min3f(m[KSEL - 1], tA, tB);
}

// uint variant (fallback kernel).
static __device__ __forceinline__ void insert2(unsigned m[KSEL], unsigned tA, unsigned tB) {
#pragma unroll
  for (int k = 0; k < KSEL - 1; ++k) {
    const unsigned mk = m[k];
    m[k] = min3u(mk, tA, tB);
    const unsigned nA = med3u(mk, tA, tB);
    const unsigned nB = max3u(mk, tA, tB);
    tA = nA;
    tB = nB;
  }
  m[KSEL - 1] = min3u(m[KSEL - 1], tA, tB);
}

// ---------------------------------------------------------------------------
// R6 post-mortem: wall-cycles per wave per group were CONSTANT ~1850 across
// R4/R5/R6 (fits VALUBusy = 8*C_group/1850 to within 3 pts in all three) —
// one full SMEM round-trip per group. Rotation prefetch never pipelined:
// SMEM is lgkmcnt-imprecise, so the compiler drains lgkmcnt(0) before the
// first use, killing any in-flight prefetch. Fix: BATCH 4 group-loads
// (4x s_load_dwordx16, issued back-to-back -> they pipeline in the memory
// system), ONE drain, then 4 groups of compute. Round-trips/segment 64 -> 16;
// per-wave latency 16*(L+4C) ~= 16us < issue-bound wall (~30us) -> latency
// fully hidden by 8-wave TLP; kernel lands on the VALU-issue floor.
// ---------------------------------------------------------------------------
template <bool EXCL>
static __device__ __forceinline__ void knn_group4(const f16v c, const int jb, const int i,
                                                  const v2f x2, const v2f y2, const v2f z2,
                                                  float m[KSEL]) {
  // layout: c[0..3]=x, c[4..7]=y, c[8..11]=z, c[12..15]=r
  v2f t01 = (v2f){c[0], c[1]} * x2;                         // x_j * (-2 x_i)
  v2f t23 = (v2f){c[2], c[3]} * x2;
  t01 = __builtin_elementwise_fma((v2f){c[4], c[5]}, y2, t01);
  t23 = __builtin_elementwise_fma((v2f){c[6], c[7]}, y2, t23);
  t01 = __builtin_elementwise_fma((v2f){c[8], c[9]}, z2, t01);
  t23 = __builtin_elementwise_fma((v2f){c[10], c[11]}, z2, t23);
  const v2f g01 = t01 + (v2f){c[12], c[13]};                // + r_j
  const v2f g23 = t23 + (v2f){c[14], c[15]};

  float gA = g01.x, gB = g01.y, gC = g23.x, gD = g23.y;
  if (EXCL) {
    if (jb + 0 == i) gA = __builtin_inff();
    if (jb + 1 == i) gB = __builtin_inff();
    if (jb + 2 == i) gC = __builtin_inff();
    if (jb + 3 == i) gD = __builtin_inff();
  }

  insert2f(m, gA, gB);
  insert2f(m, gC, gD);
}

template <bool EXCL>
static __device__ __forceinline__ void scan_seg_b4(const f16v* __restrict__ pk16,
                                                   const int j0, const int i,
                                                   const v2f x2, const v2f y2, const v2f z2,
                                                   float m[KSEL]) {
  // 16 batches x {4 s_load_dwordx16 -> one lgkm drain -> 4 groups of compute}.
  // unroll 1: two batches in flight would need 128 data SGPRs (over budget).
#pragma unroll 1
  for (int t = 0; t < SEGLEN / 16; ++t) {
    const f16v c0 = pk16[4 * t + 0];
    const f16v c1 = pk16[4 * t + 1];
    const f16v c2 = pk16[4 * t + 2];
    const f16v c3 = pk16[4 * t + 3];
    knn_group4<EXCL>(c0, j0 + 16 * t + 0,  i, x2, y2, z2, m);
    knn_group4<EXCL>(c1, j0 + 16 * t + 4,  i, x2, y2, z2, m);
    knn_group4<EXCL>(c2, j0 + 16 * t + 8,  i, x2, y2, z2, m);
    knn_group4<EXCL>(c3, j0 + 16 * t + 12, i, x2, y2, z2, m);
  }
}

// ---------------------------------------------------------------------------
// Pack: pc [8][4096][3] -> pack[8][1024] of 64B groups {x[4],y[4],z[4],r[4]}.
// One thread per group; runs once before the knn kernel. Also zeroes out[0].
// ---------------------------------------------------------------------------
__global__ __launch_bounds__(256) void pack_kernel(const float* __restrict__ pc,
                                                   float* __restrict__ pack,
                                                   float* __restrict__ out) {
  const int g = blockIdx.x * 256 + threadIdx.x;  // 0..8191 (no group crosses a batch)
  if (g == 0) out[0] = 0.0f;
  const float4 p0 = *(const float4*)(pc + g * 12 + 0);  // x0 y0 z0 x1
  const float4 p1 = *(const float4*)(pc + g * 12 + 4);  // y1 z1 x2 y2
  const float4 p2 = *(const float4*)(pc + g * 12 + 8);  // z2 x3 y3 z3
  const float x0 = p0.x, y0 = p0.y, z0 = p0.z;
  const float x1 = p0.w, y1 = p1.x, z1 = p1.y;
  const float x2 = p1.z, y2 = p1.w, z2 = p2.x;
  const float x3 = p2.y, y3 = p2.z, z3 = p2.w;
  float4* dst = (float4*)(pack + (size_t)g * 16);
  dst[0] = (float4){x0, x1, x2, x3};
  dst[1] = (float4){y0, y1, y2, y3};
  dst[2] = (float4){z0, z1, z2, z3};
  dst[3] = (float4){fmaf(z0, z0, fmaf(y0, y0, x0 * x0)),
                    fmaf(z1, z1, fmaf(y1, y1, x1 * x1)),
                    fmaf(z2, z2, fmaf(y2, y2, x2 * x2)),
                    fmaf(z3, z3, fmaf(y3, y3, x3 * x3))};
}

// ---------------------------------------------------------------------------
// Kernel 1 (fast path): per-point mean 5-NN squared distance.
// grid = 512 blocks, block = 1024 threads (16 waves). LDS = merge buffer only
// (20 KB, 2 blocks/CU). Candidates streamed via batched s_load_dwordx16.
// ---------------------------------------------------------------------------
__global__ __launch_bounds__(TPB) void knn_value_b4(const float* __restrict__ pack,
                                                    float* __restrict__ value) {
  __shared__ float cand[NSEG][64][KSEL];  // 20 KB

  const int tid = threadIdx.x;
  const int pt  = tid & 63;
  const int seg = __builtin_amdgcn_readfirstlane(tid >> 6);  // wave-uniform
  const int b    = blockIdx.x >> 6;
  const int tile = blockIdx.x & 63;
  const int i    = tile * 64 + pt;

  const float* __restrict__ pb = pack + (size_t)b * (NPTS * 4);  // 1024 groups x 16

  // Per-lane gather of point-i coords from the packed layout (once).
  const int gi = (i >> 2) * 16 + (i & 3);
  const float xi = pb[gi + 0];
  const float yi = pb[gi + 4];
  const float zi = pb[gi + 8];
  // -2*x_i is EXACT (exponent bump + sign), so g = fma(x_j, -2x_i, ...) + r_j.
  const v2f x2 = {-2.0f * xi, -2.0f * xi};
  const v2f y2 = {-2.0f * yi, -2.0f * yi};
  const v2f z2 = {-2.0f * zi, -2.0f * zi};

  float m[KSEL];
#pragma unroll
  for (int k = 0; k < KSEL; ++k) m[k] = __builtin_inff();

  const int j0 = seg * SEGLEN;
  const f16v* __restrict__ pk16 = (const f16v*)(pb) + seg * (SEGLEN / 4);

  // Tile's own 64 indices all fall in segment tile>>2 (SEGLEN=256): only that
  // wave pays the self-exclusion compares.
  if (seg == (tile >> 2)) {
    scan_seg_b4<true>(pk16, j0, i, x2, y2, z2, m);
  } else {
    scan_seg_b4<false>(pk16, j0, i, x2, y2, z2, m);
  }

#pragma unroll
  for (int k = 0; k < KSEL; ++k) cand[seg][pt][k] = m[k];
  __syncthreads();

  // Tree-merge the 16 sorted lists per point: 8,4,2,1 pairwise merges.
  for (int st = 1; st < NSEG; st <<= 1) {
    const int pairs = NSEG / (2 * st);
    if (tid < pairs * 64) {
      const int q = tid >> 6;
      const int p = tid & 63;
      float* A = &cand[2 * st * q][p][0];
      const float* B = &cand[2 * st * q + st][p][0];
      float mm[KSEL];
#pragma unroll
      for (int k = 0; k < KSEL; ++k) mm[k] = A[k];
#pragma unroll
      for (int k = 0; k < KSEL; ++k) {
        float t = B[k];
#pragma unroll
        for (int u = 0; u < KSEL - 1; ++u) {
          const float lo = fminf(mm[u], t);
          t = fmaxf(mm[u], t);
          mm[u] = lo;
        }
        mm[KSEL - 1] = fminf(mm[KSEL - 1], t);
      }
#pragma unroll
      for (int k = 0; k < KSEL; ++k) A[k] = mm[k];
    }
    __syncthreads();
  }

  // mean(d) = mean(g) + r_i. Thread tid (<64) is seg 0, pt = tid: it already
  // holds x/y/z of point i = tile*64+tid; recompute r_i with the SAME fmaf
  // form as pack_kernel (identical bits).
  if (tid < 64) {
    float s5 = 0.f;
#pragma unroll
    for (int k = 0; k < KSEL; ++k) s5 += cand[0][tid][k];
    const float ri = fmaf(zi, zi, fmaf(yi, yi, xi * xi));
    value[b * NPTS + tile * 64 + tid] = s5 * 0.2f + ri;
  }
}

// ---------------------------------------------------------------------------
// Fallback (ws too small): R1-style kernel, LDS-staged candidates,
// (a-b)^2 distances ranked via the uint-order trick. Unchanged.
// ---------------------------------------------------------------------------
template <bool EXCL>
static __device__ __forceinline__ void scan_seg_l(const float* __restrict__ xs,
                                                  const float* __restrict__ ys,
                                                  const float* __restrict__ zs,
                                                  const int j0, const int i,
                                                  const v2f nx2, const v2f ny2, const v2f nz2,
                                                  unsigned m[KSEL]) {
#pragma unroll 4
  for (int jj = 0; jj < SEGLEN; jj += 4) {
    const float4 cx = *(const float4*)&xs[j0 + jj];
    const float4 cy = *(const float4*)&ys[j0 + jj];
    const float4 cz = *(const float4*)&zs[j0 + jj];

    const v2f cxAB = {cx.x, cx.y}, cxCD = {cx.z, cx.w};
    const v2f cyAB = {cy.x, cy.y}, cyCD = {cy.z, cy.w};
    const v2f czAB = {cz.x, cz.y}, czCD = {cz.z, cz.w};

    const v2f dx0 = pk_add(cxAB, nx2);
    const v2f dx1 = pk_add(cxCD, nx2);
    const v2f dy0 = pk_add(cyAB, ny2);
    const v2f dy1 = pk_add(cyCD, ny2);
    const v2f dz0 = pk_add(czAB, nz2);
    const v2f dz1 = pk_add(czCD, nz2);

    v2f d0 = pk_mul(dx0, dx0);
    v2f d1 = pk_mul(dx1, dx1);
    d0 = pk_fma(dy0, dy0, d0);
    d1 = pk_fma(dy1, dy1, d1);
    d0 = pk_fma(dz0, dz0, d0);
    d1 = pk_fma(dz1, dz1, d1);

    unsigned uA = __float_as_uint(d0.x);
    unsigned uB = __float_as_uint(d0.y);
    unsigned uC = __float_as_uint(d1.x);
    unsigned uD = __float_as_uint(d1.y);
    if (EXCL) {
      const int jb = j0 + jj;
      if (jb + 0 == i) uA = FINF;
      if (jb + 1 == i) uB = FINF;
      if (jb + 2 == i) uC = FINF;
      if (jb + 3 == i) uD = FINF;
    }

    insert2(m, uA, uB);
    insert2(m, uC, uD);
  }
}

__global__ __launch_bounds__(TPB) void knn_value_lds(const float* __restrict__ pc,
                                                     float* __restrict__ value,
                                                     float* __restrict__ out) {
  __shared__ union __align__(16) {
    struct { float xs[NPTS]; float ys[NPTS]; float zs[NPTS]; } s;  // 48 KB
    unsigned cand[NSEG][64][KSEL];                                 // 20 KB
  } sh;

  const int tid = threadIdx.x;
  const int pt  = tid & 63;
  const int seg = __builtin_amdgcn_readfirstlane(tid >> 6);
  const int b    = blockIdx.x >> 6;
  const int tile = blockIdx.x & 63;
  const int i    = tile * 64 + pt;

  if (blockIdx.x == 0 && tid == 0) out[0] = 0.0f;

  const float* __restrict__ base = pc + (size_t)b * (NPTS * 3);

#pragma unroll
  for (int p = 0; p < NPTS / TPB; ++p) {
    const int idx = tid + p * TPB;
    sh.s.xs[idx] = base[idx * 3 + 0];
    sh.s.ys[idx] = base[idx * 3 + 1];
    sh.s.zs[idx] = base[idx * 3 + 2];
  }
  __syncthreads();

  const float xi = sh.s.xs[i];
  const float yi = sh.s.ys[i];
  const float zi = sh.s.zs[i];
  const v2f nx2 = {-xi, -xi};
  const v2f ny2 = {-yi, -yi};
  const v2f nz2 = {-zi, -zi};

  unsigned m[KSEL];
#pragma unroll
  for (int k = 0; k < KSEL; ++k) m[k] = FINF;

  const int j0 = seg * SEGLEN;
  if (seg == (tile >> 2)) {
    scan_seg_l<true>(sh.s.xs, sh.s.ys, sh.s.zs, j0, i, nx2, ny2, nz2, m);
  } else {
    scan_seg_l<false>(sh.s.xs, sh.s.ys, sh.s.zs, j0, i, nx2, ny2, nz2, m);
  }
  __syncthreads();

#pragma unroll
  for (int k = 0; k < KSEL; ++k) sh.cand[seg][pt][k] = m[k];
  __syncthreads();

  for (int st = 1; st < NSEG; st <<= 1) {
    const int pairs = NSEG / (2 * st);
    if (tid < pairs * 64) {
      const int q = tid >> 6;
      const int p = tid & 63;
      unsigned* A = &sh.cand[2 * st * q][p][0];
      const unsigned* B = &sh.cand[2 * st * q + st][p][0];
      unsigned mm[KSEL];
#pragma unroll
      for (int k = 0; k < KSEL; ++k) mm[k] = A[k];
#pragma unroll
      for (int k = 0; k < KSEL; ++k) {
        unsigned t = B[k];
#pragma unroll
        for (int u = 0; u < KSEL - 1; ++u) {
          const unsigned lo = umn(mm[u], t);
          t = umx(mm[u], t);
          mm[u] = lo;
        }
        mm[KSEL - 1] = umn(mm[KSEL - 1], t);
      }
#pragma unroll
      for (int k = 0; k < KSEL; ++k) A[k] = mm[k];
    }
    __syncthreads();
  }

  if (tid < 64) {
    float s5 = 0.f;
#pragma unroll
    for (int k = 0; k < KSEL; ++k) s5 += __uint_as_float(sh.cand[0][tid][k]);
    value[b * NPTS + tile * 64 + tid] = s5 * 0.2f;
  }
}

// ---------------------------------------------------------------------------
// Kernel 2: per-batch stats + masked mean * weight -> atomicAdd into out.
// UNCHANGED.
// ---------------------------------------------------------------------------
__global__ __launch_bounds__(256) void stats_kernel(const float* __restrict__ value,
                                                    const float* __restrict__ weights,
                                                    float* __restrict__ out) {
  __shared__ float red[256];
  const int b   = blockIdx.x;
  const int tid = threadIdx.x;
  const float* __restrict__ v = value + b * NPTS;

  float s = 0.f;
  for (int j = tid; j < NPTS; j += 256) s += v[j];
  red[tid] = s;
  __syncthreads();
  for (int off = 128; off > 0; off >>= 1) {
    if (tid < off) red[tid] += red[tid + off];
    __syncthreads();
  }
  const float mean = red[0] * (1.0f / NPTS);
  __syncthreads();

  float s2 = 0.f;
  for (int j = tid; j < NPTS; j += 256) {
    const float d = v[j] - mean;
    s2 += d * d;
  }
  red[tid] = s2;
  __syncthreads();
  for (int off = 128; off > 0; off >>= 1) {
    if (tid < off) red[tid] += red[tid + off];
    __syncthreads();
  }
  const float thr = mean + ALPHA * sqrtf(red[0] * (1.0f / (NPTS - 1)));
  __syncthreads();

  float s3 = 0.f;
  for (int j = tid; j < NPTS; j += 256) {
    const float vv = v[j];
    if (vv > thr) s3 += vv;
  }
  red[tid] = s3;
  __syncthreads();
  for (int off = 128; off > 0; off >>= 1) {
    if (tid < off) red[tid] += red[tid + off];
    __syncthreads();
  }
  if (tid == 0) {
    atomicAdd(out, red[0] * (1.0f / NPTS) * weights[b] * (1.0f / BATCH));
  }
}

extern "C" void kernel_launch(void* const* d_in, const int* in_sizes, int n_in,
                              void* d_out, int out_size, void* d_ws, size_t ws_size,
                              hipStream_t stream) {
  const float* pc      = (const float*)d_in[0];   // [8,4096,3] f32
  const float* weights = (const float*)d_in[1];   // [8] f32
  float* out   = (float*)d_out;                   // scalar f32
  float* wsf   = (float*)d_ws;

  const size_t NB = (size_t)BATCH * NPTS;         // 32768
  const size_t need = NB * 4 + NB * 4 * 4;        // value (128KB) + pack (512KB)

  if (ws_size >= need) {
    float* value = wsf;                           // 32768 floats
    float* pack  = wsf + NB;                      // 131072 floats, 64B aligned
    pack_kernel<<<dim3(BATCH * NPTS / 4 / 256), dim3(256), 0, stream>>>(pc, pack, out);
    knn_value_b4<<<dim3(BATCH * (NPTS / 64)), dim3(TPB), 0, stream>>>(pack, value);
    stats_kernel<<<dim3(BATCH), dim3(256), 0, stream>>>(value, weights, out);
  } else {
    float* value = wsf;                           // 128 KB (R1 layout)
    knn_value_lds<<<dim3(BATCH * (NPTS / 64)), dim3(TPB), 0, stream>>>(pc, value, out);
    stats_kernel<<<dim3(BATCH), dim3(256), 0, stream>>>(value, weights, out);
  }
}

// Round 8
// 104.000 us; speedup vs baseline: 1.0658x; 1.0256x over previous
//
#include <hip/hip_runtime.h>

#define BATCH 8
#define NPTS 4096
#define KSEL 5          // K_NN; self-candidate excluded in-scan
#define ALPHA 1.05f
#define NSEG 16         // candidate-scan split per point (one wave each)
#define SEGLEN (NPTS / NSEG)   // 256
#define TPB (NSEG * 64)        // 1024 threads

// ---------------------------------------------------------------------------
// f32 3-input min/med/max (single VOP3 instr each). Selection runs in FLOAT
// domain (g-scores can be negative). No NaNs present.
// ---------------------------------------------------------------------------
static __device__ __forceinline__ float min3f(float a, float b, float c) {
  float d;
  asm("v_min3_f32 %0, %1, %2, %3" : "=v"(d) : "v"(a), "v"(b), "v"(c));
  return d;
}
static __device__ __forceinline__ float med3f(float a, float b, float c) {
  float d;
  asm("v_med3_f32 %0, %1, %2, %3" : "=v"(d) : "v"(a), "v"(b), "v"(c));
  return d;
}
static __device__ __forceinline__ float max3f(float a, float b, float c) {
  float d;
  asm("v_max3_f32 %0, %1, %2, %3" : "=v"(d) : "v"(a), "v"(b), "v"(c));
  return d;
}

typedef float v2f  __attribute__((ext_vector_type(2)));
typedef float f16v __attribute__((ext_vector_type(16)));  // one 64B packed group

// Fused branchless insert of two candidates into sorted m[0..KSEL-1], float.
static __device__ __forceinline__ void insert2f(float m[KSEL], float tA, float tB) {
#pragma unroll
  for (int k = 0; k < KSEL - 1; ++k) {
    const float mk = m[k];
    m[k] = min3f(mk, tA, tB);
    const float nA = med3f(mk, tA, tB);
    const float nB = max3f(mk, tA, tB);
    tA = nA;
    tB = nB;
  }
  m[KSEL - 1] = min3f(m[KSEL - 1], tA, tB);
}

// ---------------------------------------------------------------------------
// R7 post-mortem: cycles/BYTE of SMEM traffic was the invariant across
// R4-R7 (0.9-1.1 cyc/B/CU) — the scalar cache's fill path sustains ~1 B/cyc
// per CU regardless of load width/batching, and SMEM's out-of-order returns
// force lgkmcnt(0) drains (no pipelining possible). Fix: candidate stream
// moves to LDS broadcast reads — DS return is 256 B/clk (the same 128 KB/CU
// costs ~14us, 4x less) and DS returns are IN-ORDER, so the compiler emits
// counted lgkmcnt(N) waits and the stream actually pipelines (guide §7).
// Layout: 64B packed groups {x[4],y[4],z[4],r[4]} -> 4 contiguous
// ds_read_b128 at immediate offsets, zero per-iteration address VALU.
// Distance math (34 instr/group) unchanged from R6/R7.
// ---------------------------------------------------------------------------
template <bool EXCL>
static __device__ __forceinline__ void knn_group4(const f16v c, const int jb, const int i,
                                                  const v2f x2, const v2f y2, const v2f z2,
                                                  float m[KSEL]) {
  // layout: c[0..3]=x, c[4..7]=y, c[8..11]=z, c[12..15]=r
  v2f t01 = (v2f){c[0], c[1]} * x2;                         // x_j * (-2 x_i)
  v2f t23 = (v2f){c[2], c[3]} * x2;
  t01 = __builtin_elementwise_fma((v2f){c[4], c[5]}, y2, t01);
  t23 = __builtin_elementwise_fma((v2f){c[6], c[7]}, y2, t23);
  t01 = __builtin_elementwise_fma((v2f){c[8], c[9]}, z2, t01);
  t23 = __builtin_elementwise_fma((v2f){c[10], c[11]}, z2, t23);
  const v2f g01 = t01 + (v2f){c[12], c[13]};                // + r_j
  const v2f g23 = t23 + (v2f){c[14], c[15]};

  float gA = g01.x, gB = g01.y, gC = g23.x, gD = g23.y;
  if (EXCL) {
    if (jb + 0 == i) gA = __builtin_inff();
    if (jb + 1 == i) gB = __builtin_inff();
    if (jb + 2 == i) gC = __builtin_inff();
    if (jb + 3 == i) gD = __builtin_inff();
  }

  insert2f(m, gA, gB);
  insert2f(m, gC, gD);
}

template <bool EXCL>
static __device__ __forceinline__ void scan_seg_lds(const f16v* __restrict__ sg,
                                                    const int g0, const int j0, const int i,
                                                    const v2f x2, const v2f y2, const v2f z2,
                                                    float m[KSEL]) {
  // unroll 4: 16 ds_read_b128 hoisted per unrolled body; DS in-order returns
  // let the compiler wait with counted lgkmcnt(N) and overlap read/compute.
#pragma unroll 4
  for (int g = 0; g < SEGLEN / 4; ++g) {
    const f16v c = sg[g0 + g];
    knn_group4<EXCL>(c, j0 + 4 * g, i, x2, y2, z2, m);
  }
}

// ---------------------------------------------------------------------------
// Kernel 1: per-point mean 5-NN squared distance.
// grid = 512 blocks, block = 1024 threads (16 waves). LDS = 64 KB union of
// {packed candidate groups, merge buffer} -> 2 blocks/CU (128 KB of 160 KB).
// Stage: pc -> LDS packed groups (r computed on the fly; pack kernel deleted).
// ---------------------------------------------------------------------------
__global__ __launch_bounds__(TPB) void knn_value_ldsb(const float* __restrict__ pc,
                                                      float* __restrict__ value,
                                                      float* __restrict__ out) {
  __shared__ union __align__(64) {
    float pk[NPTS * 4];              // 1024 groups x {x[4],y[4],z[4],r[4]} = 64 KB
    float cand[NSEG][64][KSEL];      // 20 KB (reused after scan)
  } sh;

  const int tid = threadIdx.x;
  const int pt  = tid & 63;
  const int seg = __builtin_amdgcn_readfirstlane(tid >> 6);  // wave-uniform
  const int b    = blockIdx.x >> 6;
  const int tile = blockIdx.x & 63;
  const int i    = tile * 64 + pt;

  if (blockIdx.x == 0 && tid == 0) out[0] = 0.0f;  // stats kernel accumulates

  // ---- Stage: 4 points per thread, packed-group layout, r on the fly ----
  const float* __restrict__ base = pc + (size_t)b * (NPTS * 3);
#pragma unroll
  for (int k = 0; k < NPTS / TPB; ++k) {
    const int p = tid + k * TPB;
    const float x = base[p * 3 + 0];
    const float y = base[p * 3 + 1];
    const float z = base[p * 3 + 2];
    float* dst = &sh.pk[(p >> 2) * 16];
    const int s = p & 3;
    dst[s + 0]  = x;
    dst[s + 4]  = y;
    dst[s + 8]  = z;
    dst[s + 12] = fmaf(z, z, fmaf(y, y, x * x));  // same form as epilogue r_i
  }
  __syncthreads();

  // Per-lane coords of point i (one-time gather from packed LDS).
  const int gi = (i >> 2) * 16 + (i & 3);
  const float xi = sh.pk[gi + 0];
  const float yi = sh.pk[gi + 4];
  const float zi = sh.pk[gi + 8];
  // -2*x_i is EXACT (exponent bump + sign) -> g = fma(x_j, -2x_i, ...) + r_j.
  const v2f x2 = {-2.0f * xi, -2.0f * xi};
  const v2f y2 = {-2.0f * yi, -2.0f * yi};
  const v2f z2 = {-2.0f * zi, -2.0f * zi};

  float m[KSEL];
#pragma unroll
  for (int k = 0; k < KSEL; ++k) m[k] = __builtin_inff();

  const int j0 = seg * SEGLEN;
  const int g0 = seg * (SEGLEN / 4);
  const f16v* __restrict__ sg = (const f16v*)sh.pk;

  // Tile's own 64 indices all fall in segment tile>>2 (SEGLEN=256): only that
  // wave pays the self-exclusion compares.
  if (seg == (tile >> 2)) {
    scan_seg_lds<true>(sg, g0, j0, i, x2, y2, z2, m);
  } else {
    scan_seg_lds<false>(sg, g0, j0, i, x2, y2, z2, m);
  }
  __syncthreads();  // all waves done reading the stage buffer

#pragma unroll
  for (int k = 0; k < KSEL; ++k) sh.cand[seg][pt][k] = m[k];
  __syncthreads();

  // Tree-merge the 16 sorted lists per point: 8,4,2,1 pairwise merges.
  for (int st = 1; st < NSEG; st <<= 1) {
    const int pairs = NSEG / (2 * st);
    if (tid < pairs * 64) {
      const int q = tid >> 6;
      const int p = tid & 63;
      float* A = &sh.cand[2 * st * q][p][0];
      const float* B = &sh.cand[2 * st * q + st][p][0];
      float mm[KSEL];
#pragma unroll
      for (int k = 0; k < KSEL; ++k) mm[k] = A[k];
#pragma unroll
      for (int k = 0; k < KSEL; ++k) {
        float t = B[k];
#pragma unroll
        for (int u = 0; u < KSEL - 1; ++u) {
          const float lo = fminf(mm[u], t);
          t = fmaxf(mm[u], t);
          mm[u] = lo;
        }
        mm[KSEL - 1] = fminf(mm[KSEL - 1], t);
      }
#pragma unroll
      for (int k = 0; k < KSEL; ++k) A[k] = mm[k];
    }
    __syncthreads();
  }

  // mean(d) = mean(g) + r_i. Thread tid (<64) is seg 0, pt = tid: it already
  // holds x/y/z of point i = tile*64+tid; r_i uses the SAME fmaf form as the
  // staged r (identical bits).
  if (tid < 64) {
    float s5 = 0.f;
#pragma unroll
    for (int k = 0; k < KSEL; ++k) s5 += sh.cand[0][tid][k];
    const float ri = fmaf(zi, zi, fmaf(yi, yi, xi * xi));
    value[b * NPTS + tile * 64 + tid] = s5 * 0.2f + ri;
  }
}

// ---------------------------------------------------------------------------
// Kernel 2: per-batch stats + masked mean * weight -> atomicAdd into out.
// UNCHANGED (bit-exact output).
// ---------------------------------------------------------------------------
__global__ __launch_bounds__(256) void stats_kernel(const float* __restrict__ value,
                                                    const float* __restrict__ weights,
                                                    float* __restrict__ out) {
  __shared__ float red[256];
  const int b   = blockIdx.x;
  const int tid = threadIdx.x;
  const float* __restrict__ v = value + b * NPTS;

  float s = 0.f;
  for (int j = tid; j < NPTS; j += 256) s += v[j];
  red[tid] = s;
  __syncthreads();
  for (int off = 128; off > 0; off >>= 1) {
    if (tid < off) red[tid] += red[tid + off];
    __syncthreads();
  }
  const float mean = red[0] * (1.0f / NPTS);
  __syncthreads();

  float s2 = 0.f;
  for (int j = tid; j < NPTS; j += 256) {
    const float d = v[j] - mean;
    s2 += d * d;
  }
  red[tid] = s2;
  __syncthreads();
  for (int off = 128; off > 0; off >>= 1) {
    if (tid < off) red[tid] += red[tid + off];
    __syncthreads();
  }
  const float thr = mean + ALPHA * sqrtf(red[0] * (1.0f / (NPTS - 1)));
  __syncthreads();

  float s3 = 0.f;
  for (int j = tid; j < NPTS; j += 256) {
    const float vv = v[j];
    if (vv > thr) s3 += vv;
  }
  red[tid] = s3;
  __syncthreads();
  for (int off = 128; off > 0; off >>= 1) {
    if (tid < off) red[tid] += red[tid + off];
    __syncthreads();
  }
  if (tid == 0) {
    atomicAdd(out, red[0] * (1.0f / NPTS) * weights[b] * (1.0f / BATCH));
  }
}

extern "C" void kernel_launch(void* const* d_in, const int* in_sizes, int n_in,
                              void* d_out, int out_size, void* d_ws, size_t ws_size,
                              hipStream_t stream) {
  const float* pc      = (const float*)d_in[0];   // [8,4096,3] f32
  const float* weights = (const float*)d_in[1];   // [8] f32
  float* out   = (float*)d_out;                   // scalar f32
  float* value = (float*)d_ws;                    // [8*4096] f32 (128 KB)

  knn_value_ldsb<<<dim3(BATCH * (NPTS / 64)), dim3(TPB), 0, stream>>>(pc, value, out);
  stats_kernel<<<dim3(BATCH), dim3(256), 0, stream>>>(value, weights, out);
}

// Round 9
// 101.515 us; speedup vs baseline: 1.0919x; 1.0245x over previous
//
#include <hip/hip_runtime.h>

#define BATCH 8
#define NPTS 4096
#define KSEL 5          // K_NN; self-candidate excluded in-scan
#define ALPHA 1.05f
#define NSEG 16         // candidate-scan split per point (one wave each)
#define SEGLEN (NPTS / NSEG)   // 256
#define TPB (NSEG * 64)        // 1024 threads
#define PPB 128         // points per block (2 per lane) — R8 post-mortem fix

// ---------------------------------------------------------------------------
// f32 3-input min/med/max (single VOP3 instr each). Selection runs in FLOAT
// domain (g-scores can be negative). No NaNs present.
// ---------------------------------------------------------------------------
static __device__ __forceinline__ float min3f(float a, float b, float c) {
  float d;
  asm("v_min3_f32 %0, %1, %2, %3" : "=v"(d) : "v"(a), "v"(b), "v"(c));
  return d;
}
static __device__ __forceinline__ float med3f(float a, float b, float c) {
  float d;
  asm("v_med3_f32 %0, %1, %2, %3" : "=v"(d) : "v"(a), "v"(b), "v"(c));
  return d;
}
static __device__ __forceinline__ float max3f(float a, float b, float c) {
  float d;
  asm("v_max3_f32 %0, %1, %2, %3" : "=v"(d) : "v"(a), "v"(b), "v"(c));
  return d;
}

typedef float v2f  __attribute__((ext_vector_type(2)));
typedef float f16v __attribute__((ext_vector_type(16)));  // one 64B packed group

// Fused branchless insert of two candidates into sorted m[0..KSEL-1], float.
static __device__ __forceinline__ void insert2f(float m[KSEL], float tA, float tB) {
#pragma unroll
  for (int k = 0; k < KSEL - 1; ++k) {
    const float mk = m[k];
    m[k] = min3f(mk, tA, tB);
    const float nA = med3f(mk, tA, tB);
    const float nB = max3f(mk, tA, tB);
    tA = nA;
    tB = nB;
  }
  m[KSEL - 1] = min3f(m[KSEL - 1], tA, tB);
}

// ---------------------------------------------------------------------------
// R8 post-mortem: VMEM/SMEM/DS all deliver ~5 B/cyc/CU to a WAVE-UNIFORM
// stream — a broadcast read replicates its 16B to 64 lanes (1KB RF traffic,
// ~12 cyc for ds_read_b128, m134), and every wave redundantly re-reads its
// whole 16KB segment. DS demand was 98k cyc/CU vs 69.5k VALU -> DS-walled.
// Fix: 2 POINTS PER LANE. Each broadcast group now retires 512 pairs instead
// of 256: DS demand halves to ~49k cyc/CU, below the VALU demand (~70k), so
// the kernel is VALU-issue-bound for the first time since R4 — at 1.7x lower
// instruction count. Distance math per point unchanged (g = r_j - 2*dot,
// pk-paired across candidates); selection = 2 independent sorted-5 lists.
// ---------------------------------------------------------------------------
template <bool EXCL>
static __device__ __forceinline__ void knn_group4_p2(const f16v c, const int jb,
                                                     const int i0, const int i1,
                                                     const v2f x20, const v2f y20, const v2f z20,
                                                     const v2f x21, const v2f y21, const v2f z21,
                                                     float m0[KSEL], float m1[KSEL]) {
  // layout: c[0..3]=x, c[4..7]=y, c[8..11]=z, c[12..15]=r
  const v2f cx01 = {c[0], c[1]}, cx23 = {c[2], c[3]};
  const v2f cy01 = {c[4], c[5]}, cy23 = {c[6], c[7]};
  const v2f cz01 = {c[8], c[9]}, cz23 = {c[10], c[11]};
  const v2f cr01 = {c[12], c[13]}, cr23 = {c[14], c[15]};

  // point 0
  v2f a01 = cx01 * x20;
  v2f a23 = cx23 * x20;
  a01 = __builtin_elementwise_fma(cy01, y20, a01);
  a23 = __builtin_elementwise_fma(cy23, y20, a23);
  a01 = __builtin_elementwise_fma(cz01, z20, a01);
  a23 = __builtin_elementwise_fma(cz23, z20, a23);
  const v2f g01_0 = a01 + cr01;
  const v2f g23_0 = a23 + cr23;

  // point 1
  v2f b01 = cx01 * x21;
  v2f b23 = cx23 * x21;
  b01 = __builtin_elementwise_fma(cy01, y21, b01);
  b23 = __builtin_elementwise_fma(cy23, y21, b23);
  b01 = __builtin_elementwise_fma(cz01, z21, b01);
  b23 = __builtin_elementwise_fma(cz23, z21, b23);
  const v2f g01_1 = b01 + cr01;
  const v2f g23_1 = b23 + cr23;

  float gA0 = g01_0.x, gB0 = g01_0.y, gC0 = g23_0.x, gD0 = g23_0.y;
  float gA1 = g01_1.x, gB1 = g01_1.y, gC1 = g23_1.x, gD1 = g23_1.y;
  if (EXCL) {
    if (jb + 0 == i0) gA0 = __builtin_inff();
    if (jb + 1 == i0) gB0 = __builtin_inff();
    if (jb + 2 == i0) gC0 = __builtin_inff();
    if (jb + 3 == i0) gD0 = __builtin_inff();
    if (jb + 0 == i1) gA1 = __builtin_inff();
    if (jb + 1 == i1) gB1 = __builtin_inff();
    if (jb + 2 == i1) gC1 = __builtin_inff();
    if (jb + 3 == i1) gD1 = __builtin_inff();
  }

  insert2f(m0, gA0, gB0);
  insert2f(m0, gC0, gD0);
  insert2f(m1, gA1, gB1);
  insert2f(m1, gC1, gD1);
}

template <bool EXCL>
static __device__ __forceinline__ void scan_seg_p2(const f16v* __restrict__ sg,
                                                   const int g0, const int j0,
                                                   const int i0, const int i1,
                                                   const v2f x20, const v2f y20, const v2f z20,
                                                   const v2f x21, const v2f y21, const v2f z21,
                                                   float m0[KSEL], float m1[KSEL]) {
  // unroll 2: 8 ds_read_b128 in flight per window; DS in-order returns get
  // counted lgkmcnt(N) waits from the compiler -> loads pipeline under VALU.
#pragma unroll 2
  for (int g = 0; g < SEGLEN / 4; ++g) {
    const f16v c = sg[g0 + g];
    knn_group4_p2<EXCL>(c, j0 + 4 * g, i0, i1, x20, y20, z20, x21, y21, z21, m0, m1);
  }
}

// ---------------------------------------------------------------------------
// Kernel 1: per-point mean 5-NN squared distance.
// grid = 256 blocks (8 batches x 32 tiles of 128 points) = 1 block/CU.
// block = 1024 threads (16 waves); each wave scans its 256-candidate segment
// for all 128 points (2/lane). LDS = 64 KB union {packed groups, merge buf}.
// ---------------------------------------------------------------------------
__global__ __launch_bounds__(TPB) void knn_value_p2(const float* __restrict__ pc,
                                                    float* __restrict__ value,
                                                    float* __restrict__ out) {
  __shared__ union __align__(64) {
    float pk[NPTS * 4];              // 1024 groups x {x[4],y[4],z[4],r[4]} = 64 KB
    float cand[NSEG][PPB][KSEL];     // 40 KB (reused after scan)
  } sh;

  const int tid = threadIdx.x;
  const int pt  = tid & 63;
  const int seg = __builtin_amdgcn_readfirstlane(tid >> 6);  // wave-uniform
  const int b    = blockIdx.x >> 5;   // 32 tiles per batch
  const int tile = blockIdx.x & 31;
  const int i0   = tile * PPB + pt;   // lane's two points
  const int i1   = i0 + 64;

  if (blockIdx.x == 0 && tid == 0) out[0] = 0.0f;  // stats kernel accumulates

  // ---- Stage: 4 points per thread, packed-group layout, r on the fly ----
  const float* __restrict__ base = pc + (size_t)b * (NPTS * 3);
#pragma unroll
  for (int k = 0; k < NPTS / TPB; ++k) {
    const int p = tid + k * TPB;
    const float x = base[p * 3 + 0];
    const float y = base[p * 3 + 1];
    const float z = base[p * 3 + 2];
    float* dst = &sh.pk[(p >> 2) * 16];
    const int s = p & 3;
    dst[s + 0]  = x;
    dst[s + 4]  = y;
    dst[s + 8]  = z;
    dst[s + 12] = fmaf(z, z, fmaf(y, y, x * x));  // same form as epilogue r_i
  }
  __syncthreads();

  // Per-lane coords of both owned points (one-time gather from packed LDS).
  const int gi0 = (i0 >> 2) * 16 + (i0 & 3);
  const int gi1 = (i1 >> 2) * 16 + (i1 & 3);
  const float xi0 = sh.pk[gi0 + 0], yi0 = sh.pk[gi0 + 4], zi0 = sh.pk[gi0 + 8];
  const float xi1 = sh.pk[gi1 + 0], yi1 = sh.pk[gi1 + 4], zi1 = sh.pk[gi1 + 8];
  // -2*x_i is EXACT (exponent bump + sign) -> g = fma(x_j, -2x_i, ...) + r_j.
  const v2f x20 = {-2.0f * xi0, -2.0f * xi0};
  const v2f y20 = {-2.0f * yi0, -2.0f * yi0};
  const v2f z20 = {-2.0f * zi0, -2.0f * zi0};
  const v2f x21 = {-2.0f * xi1, -2.0f * xi1};
  const v2f y21 = {-2.0f * yi1, -2.0f * yi1};
  const v2f z21 = {-2.0f * zi1, -2.0f * zi1};

  float m0[KSEL], m1[KSEL];
#pragma unroll
  for (int k = 0; k < KSEL; ++k) { m0[k] = __builtin_inff(); m1[k] = __builtin_inff(); }

  const int j0 = seg * SEGLEN;
  const int g0 = seg * (SEGLEN / 4);
  const f16v* __restrict__ sg = (const f16v*)sh.pk;

  // Block's 128 point indices all fall in segment tile>>1 (SEGLEN=256): only
  // that wave pays the self-exclusion compares.
  if (seg == (tile >> 1)) {
    scan_seg_p2<true>(sg, g0, j0, i0, i1, x20, y20, z20, x21, y21, z21, m0, m1);
  } else {
    scan_seg_p2<false>(sg, g0, j0, i0, i1, x20, y20, z20, x21, y21, z21, m0, m1);
  }
  __syncthreads();  // all waves done reading the stage buffer

#pragma unroll
  for (int k = 0; k < KSEL; ++k) {
    sh.cand[seg][pt][k]      = m0[k];
    sh.cand[seg][pt + 64][k] = m1[k];
  }
  __syncthreads();

  // Tree-merge the 16 sorted lists per point: 8,4,2,1 pairwise merges over
  // 128 point-columns (st=1 uses all 1024 threads).
  for (int st = 1; st < NSEG; st <<= 1) {
    const int pairs = NSEG / (2 * st);
    if (tid < pairs * PPB) {
      const int q = tid >> 7;       // pair index
      const int p = tid & (PPB - 1);
      float* A = &sh.cand[2 * st * q][p][0];
      const float* B = &sh.cand[2 * st * q + st][p][0];
      float mm[KSEL];
#pragma unroll
      for (int k = 0; k < KSEL; ++k) mm[k] = A[k];
#pragma unroll
      for (int k = 0; k < KSEL; ++k) {
        float t = B[k];
#pragma unroll
        for (int u = 0; u < KSEL - 1; ++u) {
          const float lo = fminf(mm[u], t);
          t = fmaxf(mm[u], t);
          mm[u] = lo;
        }
        mm[KSEL - 1] = fminf(mm[KSEL - 1], t);
      }
#pragma unroll
      for (int k = 0; k < KSEL; ++k) A[k] = mm[k];
    }
    __syncthreads();
  }

  // mean(d) = mean(g) + r_i. Thread tid<64 is wave 0 lane tid -> its i0 is
  // point tile*128+tid; thread 64<=tid<128 is wave 1 lane tid-64 -> its i1 is
  // point tile*128+tid. r_i recomputed with the SAME fmaf form as staging.
  if (tid < PPB) {
    float s5 = 0.f;
#pragma unroll
    for (int k = 0; k < KSEL; ++k) s5 += sh.cand[0][tid][k];
    float xx, yy, zz;
    if (tid < 64) { xx = xi0; yy = yi0; zz = zi0; }
    else          { xx = xi1; yy = yi1; zz = zi1; }
    const float ri = fmaf(zz, zz, fmaf(yy, yy, xx * xx));
    value[b * NPTS + tile * PPB + tid] = s5 * 0.2f + ri;
  }
}

// ---------------------------------------------------------------------------
// Kernel 2: per-batch stats + masked mean * weight -> atomicAdd into out.
// UNCHANGED (bit-exact output).
// ---------------------------------------------------------------------------
__global__ __launch_bounds__(256) void stats_kernel(const float* __restrict__ value,
                                                    const float* __restrict__ weights,
                                                    float* __restrict__ out) {
  __shared__ float red[256];
  const int b   = blockIdx.x;
  const int tid = threadIdx.x;
  const float* __restrict__ v = value + b * NPTS;

  float s = 0.f;
  for (int j = tid; j < NPTS; j += 256) s += v[j];
  red[tid] = s;
  __syncthreads();
  for (int off = 128; off > 0; off >>= 1) {
    if (tid < off) red[tid] += red[tid + off];
    __syncthreads();
  }
  const float mean = red[0] * (1.0f / NPTS);
  __syncthreads();

  float s2 = 0.f;
  for (int j = tid; j < NPTS; j += 256) {
    const float d = v[j] - mean;
    s2 += d * d;
  }
  red[tid] = s2;
  __syncthreads();
  for (int off = 128; off > 0; off >>= 1) {
    if (tid < off) red[tid] += red[tid + off];
    __syncthreads();
  }
  const float thr = mean + ALPHA * sqrtf(red[0] * (1.0f / (NPTS - 1)));
  __syncthreads();

  float s3 = 0.f;
  for (int j = tid; j < NPTS; j += 256) {
    const float vv = v[j];
    if (vv > thr) s3 += vv;
  }
  red[tid] = s3;
  __syncthreads();
  for (int off = 128; off > 0; off >>= 1) {
    if (tid < off) red[tid] += red[tid + off];
    __syncthreads();
  }
  if (tid == 0) {
    atomicAdd(out, red[0] * (1.0f / NPTS) * weights[b] * (1.0f / BATCH));
  }
}

extern "C" void kernel_launch(void* const* d_in, const int* in_sizes, int n_in,
                              void* d_out, int out_size, void* d_ws, size_t ws_size,
                              hipStream_t stream) {
  const float* pc      = (const float*)d_in[0];   // [8,4096,3] f32
  const float* weights = (const float*)d_in[1];   // [8] f32
  float* out   = (float*)d_out;                   // scalar f32
  float* value = (float*)d_ws;                    // [8*4096] f32 (128 KB)

  knn_value_p2<<<dim3(BATCH * (NPTS / PPB)), dim3(TPB), 0, stream>>>(pc, value, out);
  stats_kernel<<<dim3(BATCH), dim3(256), 0, stream>>>(value, weights, out);
}

// Round 10
// 98.496 us; speedup vs baseline: 1.1253x; 1.0307x over previous
//
#include <hip/hip_runtime.h>

#define BATCH 8
#define NPTS 4096
#define KSEL 5          // K_NN; self-candidate excluded in-scan
#define ALPHA 1.05f
#define NSEG 16         // candidate-scan split per point (one wave each)
#define SEGLEN (NPTS / NSEG)   // 256
#define TPB (NSEG * 64)        // 1024 threads
#define PPB 128         // points per block (2 per lane)

// ---------------------------------------------------------------------------
// f32 3-input min/med/max (single VOP3 instr each). Selection runs in FLOAT
// domain (g-scores can be negative). No NaNs present.
// ---------------------------------------------------------------------------
static __device__ __forceinline__ float min3f(float a, float b, float c) {
  float d;
  asm("v_min3_f32 %0, %1, %2, %3" : "=v"(d) : "v"(a), "v"(b), "v"(c));
  return d;
}
static __device__ __forceinline__ float med3f(float a, float b, float c) {
  float d;
  asm("v_med3_f32 %0, %1, %2, %3" : "=v"(d) : "v"(a), "v"(b), "v"(c));
  return d;
}
static __device__ __forceinline__ float max3f(float a, float b, float c) {
  float d;
  asm("v_max3_f32 %0, %1, %2, %3" : "=v"(d) : "v"(a), "v"(b), "v"(c));
  return d;
}

typedef float f16v __attribute__((ext_vector_type(16)));  // one 64B packed group

// Fused branchless insert of two candidates into sorted m[0..KSEL-1], float.
// 13 ops / 2 candidates — count-optimal for exact streaming top-5.
static __device__ __forceinline__ void insert2f(float m[KSEL], float tA, float tB) {
#pragma unroll
  for (int k = 0; k < KSEL - 1; ++k) {
    const float mk = m[k];
    m[k] = min3f(mk, tA, tB);
    const float nA = med3f(mk, tA, tB);
    const float nB = max3f(mk, tA, tB);
    tA = nA;
    tB = nB;
  }
  m[KSEL - 1] = min3f(m[KSEL - 1], tA, tB);
}

// ---------------------------------------------------------------------------
// R9 post-mortem: across R5-R9 (SMEM x4/x16/batched, LDS 1pt, LDS 2pt) the
// wall was CONSTANT ~119k cyc with busy ~= instr-count ~= 70k; no memory-path
// change moved it. The one near-saturated kernel was R4: ALL-SCALAR math,
// 94% busy at 0.94 wave-instr/cyc/CU. v_pk_*_f32 on a 32-lane SIMD is 128
// f32 lane-ops = 4 issue cyc (rate-NEUTRAL vs scalar) and empirically
// sustains only ~0.6 instr/cyc (VOP3P issue restriction). R10: all-scalar,
// minimal count:
//   g = fma(x_j,-2x_i, fma(y_j,-2y_i, fma(z_j,-2z_i, r_j)))  -> 3 instr/cand
// (r_j seeds the innermost fma; -2*x_i exact). 2-pt/lane LDS geometry kept
// (DS demand ~49k cyc/CU < VALU ~82k). Per group: 24 dist + 52 sel + ~4 ovh.
// ---------------------------------------------------------------------------
template <bool EXCL>
static __device__ __forceinline__ void knn_group4_sc(const f16v c, const int jb,
                                                     const int i0, const int i1,
                                                     const float x20, const float y20, const float z20,
                                                     const float x21, const float y21, const float z21,
                                                     float m0[KSEL], float m1[KSEL]) {
  // layout: c[0..3]=x, c[4..7]=y, c[8..11]=z, c[12..15]=r
  float g0[4], g1[4];
#pragma unroll
  for (int t = 0; t < 4; ++t) {
    const float xj = c[t], yj = c[4 + t], zj = c[8 + t], rj = c[12 + t];
    g0[t] = fmaf(xj, x20, fmaf(yj, y20, fmaf(zj, z20, rj)));
    g1[t] = fmaf(xj, x21, fmaf(yj, y21, fmaf(zj, z21, rj)));
  }
  if (EXCL) {
#pragma unroll
    for (int t = 0; t < 4; ++t) {
      if (jb + t == i0) g0[t] = __builtin_inff();
      if (jb + t == i1) g1[t] = __builtin_inff();
    }
  }
  insert2f(m0, g0[0], g0[1]);
  insert2f(m0, g0[2], g0[3]);
  insert2f(m1, g1[0], g1[1]);
  insert2f(m1, g1[2], g1[3]);
}

template <bool EXCL>
static __device__ __forceinline__ void scan_seg_sc2(const f16v* __restrict__ sg,
                                                    const int g0i, const int j0,
                                                    const int i0, const int i1,
                                                    const float x20, const float y20, const float z20,
                                                    const float x21, const float y21, const float z21,
                                                    float m0[KSEL], float m1[KSEL]) {
  // unroll 4: 16 ds_read_b128 hoisted per window; DS in-order returns get
  // counted lgkmcnt(N) waits from the compiler -> loads pipeline under VALU.
#pragma unroll 4
  for (int g = 0; g < SEGLEN / 4; ++g) {
    const f16v c = sg[g0i + g];
    knn_group4_sc<EXCL>(c, j0 + 4 * g, i0, i1, x20, y20, z20, x21, y21, z21, m0, m1);
  }
}

// ---------------------------------------------------------------------------
// Kernel 1: per-point mean 5-NN squared distance.
// grid = 256 blocks (8 batches x 32 tiles of 128 points) = 1 block/CU.
// block = 1024 threads (16 waves); each wave scans its 256-candidate segment
// for all 128 points (2/lane). LDS = 64 KB union {packed groups, merge buf}.
// ---------------------------------------------------------------------------
__global__ __launch_bounds__(TPB) void knn_value_sc2(const float* __restrict__ pc,
                                                     float* __restrict__ value,
                                                     float* __restrict__ out) {
  __shared__ union __align__(64) {
    float pk[NPTS * 4];              // 1024 groups x {x[4],y[4],z[4],r[4]} = 64 KB
    float cand[NSEG][PPB][KSEL];     // 40 KB (reused after scan)
  } sh;

  const int tid = threadIdx.x;
  const int pt  = tid & 63;
  const int seg = __builtin_amdgcn_readfirstlane(tid >> 6);  // wave-uniform
  const int b    = blockIdx.x >> 5;   // 32 tiles per batch
  const int tile = blockIdx.x & 31;
  const int i0   = tile * PPB + pt;   // lane's two points
  const int i1   = i0 + 64;

  if (blockIdx.x == 0 && tid == 0) out[0] = 0.0f;  // stats kernel accumulates

  // ---- Stage: 4 points per thread, packed-group layout, r on the fly ----
  const float* __restrict__ base = pc + (size_t)b * (NPTS * 3);
#pragma unroll
  for (int k = 0; k < NPTS / TPB; ++k) {
    const int p = tid + k * TPB;
    const float x = base[p * 3 + 0];
    const float y = base[p * 3 + 1];
    const float z = base[p * 3 + 2];
    float* dst = &sh.pk[(p >> 2) * 16];
    const int s = p & 3;
    dst[s + 0]  = x;
    dst[s + 4]  = y;
    dst[s + 8]  = z;
    dst[s + 12] = fmaf(z, z, fmaf(y, y, x * x));  // same form as epilogue r_i
  }
  __syncthreads();

  // Per-lane coords of both owned points (one-time gather from packed LDS).
  const int gi0 = (i0 >> 2) * 16 + (i0 & 3);
  const int gi1 = (i1 >> 2) * 16 + (i1 & 3);
  const float xi0 = sh.pk[gi0 + 0], yi0 = sh.pk[gi0 + 4], zi0 = sh.pk[gi0 + 8];
  const float xi1 = sh.pk[gi1 + 0], yi1 = sh.pk[gi1 + 4], zi1 = sh.pk[gi1 + 8];
  // -2*x_i is EXACT (exponent bump + sign).
  const float x20 = -2.0f * xi0, y20 = -2.0f * yi0, z20 = -2.0f * zi0;
  const float x21 = -2.0f * xi1, y21 = -2.0f * yi1, z21 = -2.0f * zi1;

  float m0[KSEL], m1[KSEL];
#pragma unroll
  for (int k = 0; k < KSEL; ++k) { m0[k] = __builtin_inff(); m1[k] = __builtin_inff(); }

  const int j0  = seg * SEGLEN;
  const int g0i = seg * (SEGLEN / 4);
  const f16v* __restrict__ sg = (const f16v*)sh.pk;

  // Block's 128 point indices all fall in segment tile>>1 (SEGLEN=256): only
  // that wave pays the self-exclusion compares.
  if (seg == (tile >> 1)) {
    scan_seg_sc2<true>(sg, g0i, j0, i0, i1, x20, y20, z20, x21, y21, z21, m0, m1);
  } else {
    scan_seg_sc2<false>(sg, g0i, j0, i0, i1, x20, y20, z20, x21, y21, z21, m0, m1);
  }
  __syncthreads();  // all waves done reading the stage buffer

#pragma unroll
  for (int k = 0; k < KSEL; ++k) {
    sh.cand[seg][pt][k]      = m0[k];
    sh.cand[seg][pt + 64][k] = m1[k];
  }
  __syncthreads();

  // Tree-merge the 16 sorted lists per point: 8,4,2,1 pairwise merges over
  // 128 point-columns (st=1 uses all 1024 threads).
  for (int st = 1; st < NSEG; st <<= 1) {
    const int pairs = NSEG / (2 * st);
    if (tid < pairs * PPB) {
      const int q = tid >> 7;       // pair index
      const int p = tid & (PPB - 1);
      float* A = &sh.cand[2 * st * q][p][0];
      const float* B = &sh.cand[2 * st * q + st][p][0];
      float mm[KSEL];
#pragma unroll
      for (int k = 0; k < KSEL; ++k) mm[k] = A[k];
#pragma unroll
      for (int k = 0; k < KSEL; ++k) {
        float t = B[k];
#pragma unroll
        for (int u = 0; u < KSEL - 1; ++u) {
          const float lo = fminf(mm[u], t);
          t = fmaxf(mm[u], t);
          mm[u] = lo;
        }
        mm[KSEL - 1] = fminf(mm[KSEL - 1], t);
      }
#pragma unroll
      for (int k = 0; k < KSEL; ++k) A[k] = mm[k];
    }
    __syncthreads();
  }

  // mean(d) = mean(g) + r_i. Thread tid<64 is wave 0 lane tid -> its i0 is
  // point tile*128+tid; 64<=tid<128 is wave 1 lane tid-64 -> its i1 is point
  // tile*128+tid. r_i recomputed with the SAME fmaf form as staging.
  if (tid < PPB) {
    float s5 = 0.f;
#pragma unroll
    for (int k = 0; k < KSEL; ++k) s5 += sh.cand[0][tid][k];
    float xx, yy, zz;
    if (tid < 64) { xx = xi0; yy = yi0; zz = zi0; }
    else          { xx = xi1; yy = yi1; zz = zi1; }
    const float ri = fmaf(zz, zz, fmaf(yy, yy, xx * xx));
    value[b * NPTS + tile * PPB + tid] = s5 * 0.2f + ri;
  }
}

// ---------------------------------------------------------------------------
// Kernel 2: per-batch stats + masked mean * weight -> atomicAdd into out.
// UNCHANGED (bit-exact output).
// ---------------------------------------------------------------------------
__global__ __launch_bounds__(256) void stats_kernel(const float* __restrict__ value,
                                                    const float* __restrict__ weights,
                                                    float* __restrict__ out) {
  __shared__ float red[256];
  const int b   = blockIdx.x;
  const int tid = threadIdx.x;
  const float* __restrict__ v = value + b * NPTS;

  float s = 0.f;
  for (int j = tid; j < NPTS; j += 256) s += v[j];
  red[tid] = s;
  __syncthreads();
  for (int off = 128; off > 0; off >>= 1) {
    if (tid < off) red[tid] += red[tid + off];
    __syncthreads();
  }
  const float mean = red[0] * (1.0f / NPTS);
  __syncthreads();

  float s2 = 0.f;
  for (int j = tid; j < NPTS; j += 256) {
    const float d = v[j] - mean;
    s2 += d * d;
  }
  red[tid] = s2;
  __syncthreads();
  for (int off = 128; off > 0; off >>= 1) {
    if (tid < off) red[tid] += red[tid + off];
    __syncthreads();
  }
  const float thr = mean + ALPHA * sqrtf(red[0] * (1.0f / (NPTS - 1)));
  __syncthreads();

  float s3 = 0.f;
  for (int j = tid; j < NPTS; j += 256) {
    const float vv = v[j];
    if (vv > thr) s3 += vv;
  }
  red[tid] = s3;
  __syncthreads();
  for (int off = 128; off > 0; off >>= 1) {
    if (tid < off) red[tid] += red[tid + off];
    __syncthreads();
  }
  if (tid == 0) {
    atomicAdd(out, red[0] * (1.0f / NPTS) * weights[b] * (1.0f / BATCH));
  }
}

extern "C" void kernel_launch(void* const* d_in, const int* in_sizes, int n_in,
                              void* d_out, int out_size, void* d_ws, size_t ws_size,
                              hipStream_t stream) {
  const float* pc      = (const float*)d_in[0];   // [8,4096,3] f32
  const float* weights = (const float*)d_in[1];   // [8] f32
  float* out   = (float*)d_out;                   // scalar f32
  float* value = (float*)d_ws;                    // [8*4096] f32 (128 KB)

  knn_value_sc2<<<dim3(BATCH * (NPTS / PPB)), dim3(TPB), 0, stream>>>(pc, value, out);
  stats_kernel<<<dim3(BATCH), dim3(256), 0, stream>>>(value, weights, out);
}